// Round 11
// baseline (132.339 us; speedup 1.0000x reference)
//
#include <hip/hip_runtime.h>
#include <hip/hip_fp16.h>

#define HH 256
#define WW 704
#define DD 64
#define CC 3
#define BB 2
#define HWN (HH * WW)       // 180224

#define TY 8                // out-tile rows
#define TX 8                // out-tile cols
#define RY0 12              // q0 region rows (tile + 2*2 halo)
#define RX0 12              // q0 region cols
#define NP0 (RY0 * RX0)     // 144
#define RY1 10              // q1 region rows (tile + 2*1 halo)
#define RX1 10              // q1 region cols
#define NP1 (RY1 * RX1)     // 100
#define NTX (WW / TX)       // 88
#define NTY (HH / TY)       // 32
#define NTILES (NTX * NTY)  // 2816 (divisible by 8 -> bijective XCD swizzle)

static constexpr float INV2Z2 = 1.0f / (2.0f * 1e-3f * 1e-3f);

// ---------------------------------------------------------------------------
// Affinity (r6 version, 1 px/thread — known-good occupancy):
// kaff[b,k,n] = ws * exp(-sum_c (uc-c)^2/(2 zeta^2)); zero-pad semantics.
// ---------------------------------------------------------------------------
__global__ __launch_bounds__(256) void affinity_kernel(
    const float* __restrict__ color, const float* __restrict__ wsp,
    float* __restrict__ kaff)
{
    int n = blockIdx.x * 256 + threadIdx.x;
    int b = blockIdx.y;
    int h = n / WW, w = n - h * WW;
    float wsv = wsp[0];

    const float* cb = color + (size_t)b * CC * HWN + n;
    float c0 = cb[0], c1 = cb[HWN], c2 = cb[2 * HWN];
    bool hm = h > 0, hp = h < HH - 1, wm = w > 0, wp = w < WW - 1;

    float* kb = kaff + (size_t)b * 9 * HWN + n;
#pragma unroll
    for (int dh = -1; dh <= 1; ++dh) {
#pragma unroll
        for (int dw = -1; dw <= 1; ++dw) {
            int k = (dh + 1) * 3 + (dw + 1);
            bool valid = (dh < 0 ? hm : (dh > 0 ? hp : true)) &&
                         (dw < 0 ? wm : (dw > 0 ? wp : true));
            int off = valid ? (dh * WW + dw) : 0;
            float u0 = valid ? cb[off] : 0.f;
            float u1 = valid ? cb[HWN + off] : 0.f;
            float u2 = valid ? cb[2 * HWN + off] : 0.f;
            float d0 = u0 - c0, d1 = u1 - c1, d2 = u2 - c2;
            float ss = d0 * d0 + d1 * d1 + d2 * d2;
            kb[(size_t)k * HWN] = wsv * __expf(-ss * INV2Z2);
        }
    }
}

// ---------------------------------------------------------------------------
// LDS layout: px-major, 32 dwords (64 f16 ch) per px, XOR swizzle on dword
// index: dw(p,q) = p*32 + (q ^ ((p&7)<<2)). Same permutation on store and
// load -> correctness independent of the mixing.
// ---------------------------------------------------------------------------
__device__ __forceinline__ void acc_tap(const unsigned* q, int p0, int cg,
                                        __half2 kh, __half2* tv2) {
    int ia = p0 * 32 + ((cg * 8) ^ ((p0 & 7) << 2));
    int ib = ia ^ 4;
    const __half2* qa = (const __half2*)&q[ia];
    const __half2* qb = (const __half2*)&q[ib];
    tv2[0] = __hfma2(kh, qa[0], tv2[0]);
    tv2[1] = __hfma2(kh, qa[1], tv2[1]);
    tv2[2] = __hfma2(kh, qa[2], tv2[2]);
    tv2[3] = __hfma2(kh, qa[3], tv2[3]);
    tv2[4] = __hfma2(kh, qb[0], tv2[4]);
    tv2[5] = __hfma2(kh, qb[1], tv2[5]);
    tv2[6] = __hfma2(kh, qb[2], tv2[6]);
    tv2[7] = __hfma2(kh, qb[3], tv2[7]);
}

__device__ __forceinline__ void st_px(unsigned* q, int p, int cg,
                                      const float* u, float scale) {
    int ia = p * 32 + ((cg * 8) ^ ((p & 7) << 2));
    int ib = ia ^ 4;
    __half2* qa = (__half2*)&q[ia];
    __half2* qb = (__half2*)&q[ib];
    qa[0] = __floats2half2_rn(u[0]  * scale, u[1]  * scale);
    qa[1] = __floats2half2_rn(u[2]  * scale, u[3]  * scale);
    qa[2] = __floats2half2_rn(u[4]  * scale, u[5]  * scale);
    qa[3] = __floats2half2_rn(u[6]  * scale, u[7]  * scale);
    qb[0] = __floats2half2_rn(u[8]  * scale, u[9]  * scale);
    qb[1] = __floats2half2_rn(u[10] * scale, u[11] * scale);
    qb[2] = __floats2half2_rn(u[12] * scale, u[13] * scale);
    qb[3] = __floats2half2_rn(u[14] * scale, u[15] * scale);
}

__device__ __forceinline__ void scan4(float Aloc, float Bloc, int pxl, int cg,
                                      float& Ar, float& Br, float& T, float& E) {
    float A0 = __shfl(Aloc, pxl),      A1 = __shfl(Aloc, pxl + 16),
          A2 = __shfl(Aloc, pxl + 32), A3 = __shfl(Aloc, pxl + 48);
    float B0 = __shfl(Bloc, pxl),      B1 = __shfl(Bloc, pxl + 16),
          B2 = __shfl(Bloc, pxl + 32), B3 = __shfl(Bloc, pxl + 48);
    T = A0 + A1 + A2 + A3;  E = B0 + B1 + B2 + B3;
    Ar = 0.f; Br = 0.f;
    if (cg > 0) { Ar += A0; Br += B0; }
    if (cg > 1) { Ar += A1; Br += B1; }
    if (cg > 2) { Ar += A2; Br += B2; }
}

__device__ __forceinline__ float finish_px(float* tv, const float* lgv,
                                           int pxl, int cg) {
    float Aloc = 0.f, Bloc = 0.f;
#pragma unroll
    for (int i = 0; i < 16; ++i) {
        float e = (float)(cg * 16 + i);
        Aloc += tv[i]; Bloc += e * tv[i];
    }
    float Ar, Br, T, E;
    scan4(Aloc, Bloc, pxl, cg, Ar, Br, T, E);
    float s = 0.f;
#pragma unroll
    for (int i = 0; i < 16; ++i) {
        float e = (float)(cg * 16 + i);
        Ar += tv[i]; Br += e * tv[i];
        float v = lgv[i] - (2.f * (e * Ar - Br) + E - e * T);
        tv[i] = __expf(v); s += tv[i];
    }
    s += __shfl_xor(s, 16);
    s += __shfl_xor(s, 32);
    return 1.f / s;
}

__device__ __forceinline__ void load_k(const float* kfb, int n, int gy, int gx,
                                       float* k) {
#pragma unroll
    for (int j = 0; j < 9; ++j) k[j] = kfb[(size_t)j * HWN + n];
    if (gy <= 0)      { k[0] = k[1] = k[2] = 0.f; }
    if (gy >= HH - 1) { k[6] = k[7] = k[8] = 0.f; }
    if (gx <= 0)      { k[0] = k[3] = k[6] = 0.f; }
    if (gx >= WW - 1) { k[2] = k[5] = k[8] = 0.f; }
}

// 9-tap stencil from an LDS q-region into tv[16] (f32), via packed f16 FMA
__device__ __forceinline__ void stencil9(const unsigned* qs, int rowstride,
                                         int py, int px, int cg,
                                         const float* k, float* tv) {
    __half2 tv2[8];
#pragma unroll
    for (int j = 0; j < 8; ++j) tv2[j] = __float2half2_rn(0.f);
    int base = (py + 1) * rowstride + (px + 1);
#pragma unroll
    for (int tap = 0; tap < 9; ++tap) {
        int dy = tap / 3 - 1, dx = tap - (tap / 3) * 3 - 1;
        acc_tap(qs, base + dy * rowstride + dx, cg, __float2half2_rn(k[tap]), tv2);
    }
#pragma unroll
    for (int j = 0; j < 8; ++j) {
        float2 f = __half22float2(tv2[j]);
        tv[2 * j] = f.x; tv[2 * j + 1] = f.y;
    }
}

// ---------------------------------------------------------------------------
// Fused CRF per 8x8 out-tile (task = 1 px, 4 lanes x 16 ch):
//   P0: q0 = softmax(logits) on 12x12 -> LDS f16
//   P1: q1 = iter(q0) on 10x10 -> LDS f16
//   P2: q2 = iter(q1) on 8x8 -> global
// LDS 31.2 KB allows 5 blocks/CU; __launch_bounds__(256, 5) pins the
// register budget to ~102 VGPR so the compiler does NOT spill to scratch
// chasing 8+ waves/SIMD (r10: VGPR=52, +30 MB spill writes, regression).
// ---------------------------------------------------------------------------
__global__ __launch_bounds__(256, 5) void fused_crf_kernel(
    const float* __restrict__ logits, const float* __restrict__ kaff,
    float* __restrict__ qout)
{
    __shared__ unsigned q0s[NP0 * 32];   // 18,432 B
    __shared__ unsigned q1s[NP1 * 32];   // 12,800 B

    const int t = threadIdx.x;
    const int lane = t & 63;
    const int wv = t >> 6;          // 0..3
    const int pxl = lane & 15;
    const int cg = lane >> 4;       // channels [16cg, 16cg+16)
    const int b = blockIdx.y;

    const int bid = blockIdx.x;     // XCD swizzle (2816 % 8 == 0 -> bijective)
    const int pb = (bid & 7) * (NTILES / 8) + (bid >> 3);
    const int tyr = pb / NTX, txc = pb - tyr * NTX;
    const int y0 = tyr * TY, x0 = txc * TX;

    const float* lgb = logits + ((size_t)b * DD + cg * 16) * HWN;
    const float* kfb = kaff + (size_t)b * 9 * HWN;

    // ---------------- P0: q0 = softmax(logits) on 12x12 ----------------
    for (int r = 0; r < 3; ++r) {
        int id = r * 64 + wv * 16 + pxl;
        if (id < NP0) {
            int py = id / RX0, px = id - py * RX0;
            int gy = min(max(y0 - 2 + py, 0), HH - 1);
            int gx = min(max(x0 - 2 + px, 0), WW - 1);
            const float* lg = lgb + gy * WW + gx;
            float v[16];
            float s = 0.f;
#pragma unroll
            for (int i = 0; i < 16; ++i) {
                v[i] = __expf(lg[(size_t)i * HWN]);
                s += v[i];
            }
            s += __shfl_xor(s, 16);
            s += __shfl_xor(s, 32);
            st_px(q0s, id, cg, v, 1.0f / s);
        }
    }
    __syncthreads();

    // ---------------- P1: q1 = iter(q0) on 10x10 ----------------
    for (int r = 0; r < 2; ++r) {
        int id = r * 64 + wv * 16 + pxl;
        if (id < NP1) {
            int py = id / RX1, px = id - py * RX1;
            int gy = y0 - 1 + py, gx = x0 - 1 + px;   // may be out of image
            int cy = min(max(gy, 0), HH - 1), cx = min(max(gx, 0), WW - 1);
            int n = cy * WW + cx;

            float k[9];
            load_k(kfb, n, gy, gx, k);
            const float* lgn = lgb + n;
            float lgv[16];
#pragma unroll
            for (int i = 0; i < 16; ++i) lgv[i] = lgn[(size_t)i * HWN];

            float tv[16];
            stencil9(q0s, RX0, py, px, cg, k, tv);
            float inv = finish_px(tv, lgv, pxl, cg);
            st_px(q1s, id, cg, tv, inv);
        }
    }
    __syncthreads();

    // ---------------- P2: q2 = iter(q1) -> global, 8x8 ----------------
    {
        int id = wv * 16 + pxl;              // 0..63, all valid
        int py = id >> 3, px = id & 7;
        int gy = y0 + py, gx = x0 + px;      // always in image
        int n = gy * WW + gx;

        float k[9];
        load_k(kfb, n, gy, gx, k);
        const float* lgn = lgb + n;
        float lgv[16];
#pragma unroll
        for (int i = 0; i < 16; ++i) lgv[i] = lgn[(size_t)i * HWN];

        float tv[16];
        stencil9(q1s, RX1, py, px, cg, k, tv);
        float inv = finish_px(tv, lgv, pxl, cg);

        float* qo = qout + ((size_t)b * DD + cg * 16) * HWN + n;
#pragma unroll
        for (int i = 0; i < 16; ++i) qo[(size_t)i * HWN] = tv[i] * inv;
    }
}

// ---------------------------------------------------------------------------
extern "C" void kernel_launch(void* const* d_in, const int* in_sizes, int n_in,
                              void* d_out, int out_size, void* d_ws, size_t ws_size,
                              hipStream_t stream) {
    const float* color  = (const float*)d_in[0];
    // d_in[1] = feats: unused by the forward pass
    const float* logits = (const float*)d_in[2];
    const float* wsp    = (const float*)d_in[3];

    float* q_out = (float*)d_out;
    float* kaff  = (float*)d_ws;          // [B,9,HW] f32, 13 MB

    dim3 gridA(HWN / 256, BB);
    affinity_kernel<<<gridA, 256, 0, stream>>>(color, wsp, kaff);

    dim3 gridF(NTILES, BB);               // 2816 tiles x 2 batches
    fused_crf_kernel<<<gridF, 256, 0, stream>>>(logits, kaff, q_out);
}

// Round 12
// 124.351 us; speedup vs baseline: 1.0642x; 1.0642x over previous
//
#include <hip/hip_runtime.h>
#include <hip/hip_fp16.h>

#define HH 256
#define WW 704
#define DD 64
#define CC 3
#define BB 2
#define HWN (HH * WW)       // 180224

#define TY 8                // out-tile rows
#define TX 8                // out-tile cols
#define RY0 12              // q0 region rows (tile + 2*2 halo)
#define RX0 12              // q0 region cols
#define NP0 (RY0 * RX0)     // 144
#define RY1 10              // q1 region rows (tile + 2*1 halo)
#define RX1 10              // q1 region cols
#define NP1 (RY1 * RX1)     // 100
#define NTX (WW / TX)       // 88
#define NTY (HH / TY)       // 32
#define NTILES (NTX * NTY)  // 2816 (divisible by 8 -> bijective XCD swizzle)

static constexpr float INV2Z2 = 1.0f / (2.0f * 1e-3f * 1e-3f);

// ---------------------------------------------------------------------------
// Affinity (r6 version, 1 px/thread — known-good occupancy):
// kaff[b,k,n] = ws * exp(-sum_c (uc-c)^2/(2 zeta^2)); zero-pad semantics.
// ---------------------------------------------------------------------------
__global__ __launch_bounds__(256) void affinity_kernel(
    const float* __restrict__ color, const float* __restrict__ wsp,
    float* __restrict__ kaff)
{
    int n = blockIdx.x * 256 + threadIdx.x;
    int b = blockIdx.y;
    int h = n / WW, w = n - h * WW;
    float wsv = wsp[0];

    const float* cb = color + (size_t)b * CC * HWN + n;
    float c0 = cb[0], c1 = cb[HWN], c2 = cb[2 * HWN];
    bool hm = h > 0, hp = h < HH - 1, wm = w > 0, wp = w < WW - 1;

    float* kb = kaff + (size_t)b * 9 * HWN + n;
#pragma unroll
    for (int dh = -1; dh <= 1; ++dh) {
#pragma unroll
        for (int dw = -1; dw <= 1; ++dw) {
            int k = (dh + 1) * 3 + (dw + 1);
            bool valid = (dh < 0 ? hm : (dh > 0 ? hp : true)) &&
                         (dw < 0 ? wm : (dw > 0 ? wp : true));
            int off = valid ? (dh * WW + dw) : 0;
            float u0 = valid ? cb[off] : 0.f;
            float u1 = valid ? cb[HWN + off] : 0.f;
            float u2 = valid ? cb[2 * HWN + off] : 0.f;
            float d0 = u0 - c0, d1 = u1 - c1, d2 = u2 - c2;
            float ss = d0 * d0 + d1 * d1 + d2 * d2;
            kb[(size_t)k * HWN] = wsv * __expf(-ss * INV2Z2);
        }
    }
}

// ---------------------------------------------------------------------------
// LDS layout: px-major, 32 dwords (64 f16 ch) per px, XOR swizzle on dword
// index: dw(p,q) = p*32 + (q ^ ((p&7)<<2)). Same permutation on store and
// load -> correctness independent of the mixing.
// ---------------------------------------------------------------------------
__device__ __forceinline__ void acc_tap(const unsigned* q, int p0, int cg,
                                        __half2 kh, __half2* tv2) {
    int ia = p0 * 32 + ((cg * 8) ^ ((p0 & 7) << 2));
    int ib = ia ^ 4;
    const __half2* qa = (const __half2*)&q[ia];
    const __half2* qb = (const __half2*)&q[ib];
    tv2[0] = __hfma2(kh, qa[0], tv2[0]);
    tv2[1] = __hfma2(kh, qa[1], tv2[1]);
    tv2[2] = __hfma2(kh, qa[2], tv2[2]);
    tv2[3] = __hfma2(kh, qa[3], tv2[3]);
    tv2[4] = __hfma2(kh, qb[0], tv2[4]);
    tv2[5] = __hfma2(kh, qb[1], tv2[5]);
    tv2[6] = __hfma2(kh, qb[2], tv2[6]);
    tv2[7] = __hfma2(kh, qb[3], tv2[7]);
}

__device__ __forceinline__ void st_px(unsigned* q, int p, int cg,
                                      const float* u, float scale) {
    int ia = p * 32 + ((cg * 8) ^ ((p & 7) << 2));
    int ib = ia ^ 4;
    __half2* qa = (__half2*)&q[ia];
    __half2* qb = (__half2*)&q[ib];
    qa[0] = __floats2half2_rn(u[0]  * scale, u[1]  * scale);
    qa[1] = __floats2half2_rn(u[2]  * scale, u[3]  * scale);
    qa[2] = __floats2half2_rn(u[4]  * scale, u[5]  * scale);
    qa[3] = __floats2half2_rn(u[6]  * scale, u[7]  * scale);
    qb[0] = __floats2half2_rn(u[8]  * scale, u[9]  * scale);
    qb[1] = __floats2half2_rn(u[10] * scale, u[11] * scale);
    qb[2] = __floats2half2_rn(u[12] * scale, u[13] * scale);
    qb[3] = __floats2half2_rn(u[14] * scale, u[15] * scale);
}

__device__ __forceinline__ void scan4(float Aloc, float Bloc, int pxl, int cg,
                                      float& Ar, float& Br, float& T, float& E) {
    float A0 = __shfl(Aloc, pxl),      A1 = __shfl(Aloc, pxl + 16),
          A2 = __shfl(Aloc, pxl + 32), A3 = __shfl(Aloc, pxl + 48);
    float B0 = __shfl(Bloc, pxl),      B1 = __shfl(Bloc, pxl + 16),
          B2 = __shfl(Bloc, pxl + 32), B3 = __shfl(Bloc, pxl + 48);
    T = A0 + A1 + A2 + A3;  E = B0 + B1 + B2 + B3;
    Ar = 0.f; Br = 0.f;
    if (cg > 0) { Ar += A0; Br += B0; }
    if (cg > 1) { Ar += A1; Br += B1; }
    if (cg > 2) { Ar += A2; Br += B2; }
}

__device__ __forceinline__ float finish_px(float* tv, const float* lgv,
                                           int pxl, int cg) {
    float Aloc = 0.f, Bloc = 0.f;
#pragma unroll
    for (int i = 0; i < 16; ++i) {
        float e = (float)(cg * 16 + i);
        Aloc += tv[i]; Bloc += e * tv[i];
    }
    float Ar, Br, T, E;
    scan4(Aloc, Bloc, pxl, cg, Ar, Br, T, E);
    float s = 0.f;
#pragma unroll
    for (int i = 0; i < 16; ++i) {
        float e = (float)(cg * 16 + i);
        Ar += tv[i]; Br += e * tv[i];
        float v = lgv[i] - (2.f * (e * Ar - Br) + E - e * T);
        tv[i] = __expf(v); s += tv[i];
    }
    s += __shfl_xor(s, 16);
    s += __shfl_xor(s, 32);
    return 1.f / s;
}

__device__ __forceinline__ void load_k(const float* kfb, int n, int gy, int gx,
                                       float* k) {
#pragma unroll
    for (int j = 0; j < 9; ++j) k[j] = kfb[(size_t)j * HWN + n];
    if (gy <= 0)      { k[0] = k[1] = k[2] = 0.f; }
    if (gy >= HH - 1) { k[6] = k[7] = k[8] = 0.f; }
    if (gx <= 0)      { k[0] = k[3] = k[6] = 0.f; }
    if (gx >= WW - 1) { k[2] = k[5] = k[8] = 0.f; }
}

// 9-tap stencil from an LDS q-region into tv[16] (f32), via packed f16 FMA
__device__ __forceinline__ void stencil9(const unsigned* qs, int rowstride,
                                         int py, int px, int cg,
                                         const float* k, float* tv) {
    __half2 tv2[8];
#pragma unroll
    for (int j = 0; j < 8; ++j) tv2[j] = __float2half2_rn(0.f);
    int base = (py + 1) * rowstride + (px + 1);
#pragma unroll
    for (int tap = 0; tap < 9; ++tap) {
        int dy = tap / 3 - 1, dx = tap - (tap / 3) * 3 - 1;
        acc_tap(qs, base + dy * rowstride + dx, cg, __float2half2_rn(k[tap]), tv2);
    }
#pragma unroll
    for (int j = 0; j < 8; ++j) {
        float2 f = __half22float2(tv2[j]);
        tv[2 * j] = f.x; tv[2 * j + 1] = f.y;
    }
}

// ---------------------------------------------------------------------------
// Fused CRF per 8x8 out-tile (task = 1 px, 4 lanes x 16 ch):
//   P0: q0 = softmax(logits) on 12x12 -> LDS f16
//   P1: q1 = iter(q0) on 10x10 -> LDS f16
//   P2: q2 = iter(q1) on 8x8 -> global
// LDS 31.2 KB -> 5 blocks/CU.  amdgpu_waves_per_eu(2,5): max=5 tells the
// allocator that occupancy beyond the LDS cap (5 waves/EU) is useless, so it
// must NOT squeeze VGPRs below ~102 (r10/r11: squeezed to 48-52 -> ~35 MB
// scratch spills); min=2 leaves the budget cap at 256 so ~84 live regs fit.
// ---------------------------------------------------------------------------
__global__ __launch_bounds__(256)
__attribute__((amdgpu_waves_per_eu(2, 5)))
void fused_crf_kernel(
    const float* __restrict__ logits, const float* __restrict__ kaff,
    float* __restrict__ qout)
{
    __shared__ unsigned q0s[NP0 * 32];   // 18,432 B
    __shared__ unsigned q1s[NP1 * 32];   // 12,800 B

    const int t = threadIdx.x;
    const int lane = t & 63;
    const int wv = t >> 6;          // 0..3
    const int pxl = lane & 15;
    const int cg = lane >> 4;       // channels [16cg, 16cg+16)
    const int b = blockIdx.y;

    const int bid = blockIdx.x;     // XCD swizzle (2816 % 8 == 0 -> bijective)
    const int pb = (bid & 7) * (NTILES / 8) + (bid >> 3);
    const int tyr = pb / NTX, txc = pb - tyr * NTX;
    const int y0 = tyr * TY, x0 = txc * TX;

    const float* lgb = logits + ((size_t)b * DD + cg * 16) * HWN;
    const float* kfb = kaff + (size_t)b * 9 * HWN;

    // ---------------- P0: q0 = softmax(logits) on 12x12 ----------------
    for (int r = 0; r < 3; ++r) {
        int id = r * 64 + wv * 16 + pxl;
        if (id < NP0) {
            int py = id / RX0, px = id - py * RX0;
            int gy = min(max(y0 - 2 + py, 0), HH - 1);
            int gx = min(max(x0 - 2 + px, 0), WW - 1);
            const float* lg = lgb + gy * WW + gx;
            float v[16];
            float s = 0.f;
#pragma unroll
            for (int i = 0; i < 16; ++i) {
                v[i] = __expf(lg[(size_t)i * HWN]);
                s += v[i];
            }
            s += __shfl_xor(s, 16);
            s += __shfl_xor(s, 32);
            st_px(q0s, id, cg, v, 1.0f / s);
        }
    }
    __syncthreads();

    // ---------------- P1: q1 = iter(q0) on 10x10 ----------------
    for (int r = 0; r < 2; ++r) {
        int id = r * 64 + wv * 16 + pxl;
        if (id < NP1) {
            int py = id / RX1, px = id - py * RX1;
            int gy = y0 - 1 + py, gx = x0 - 1 + px;   // may be out of image
            int cy = min(max(gy, 0), HH - 1), cx = min(max(gx, 0), WW - 1);
            int n = cy * WW + cx;

            float k[9];
            load_k(kfb, n, gy, gx, k);
            const float* lgn = lgb + n;
            float lgv[16];
#pragma unroll
            for (int i = 0; i < 16; ++i) lgv[i] = lgn[(size_t)i * HWN];

            float tv[16];
            stencil9(q0s, RX0, py, px, cg, k, tv);
            float inv = finish_px(tv, lgv, pxl, cg);
            st_px(q1s, id, cg, tv, inv);
        }
    }
    __syncthreads();

    // ---------------- P2: q2 = iter(q1) -> global, 8x8 ----------------
    {
        int id = wv * 16 + pxl;              // 0..63, all valid
        int py = id >> 3, px = id & 7;
        int gy = y0 + py, gx = x0 + px;      // always in image
        int n = gy * WW + gx;

        float k[9];
        load_k(kfb, n, gy, gx, k);
        const float* lgn = lgb + n;
        float lgv[16];
#pragma unroll
        for (int i = 0; i < 16; ++i) lgv[i] = lgn[(size_t)i * HWN];

        float tv[16];
        stencil9(q1s, RX1, py, px, cg, k, tv);
        float inv = finish_px(tv, lgv, pxl, cg);

        float* qo = qout + ((size_t)b * DD + cg * 16) * HWN + n;
#pragma unroll
        for (int i = 0; i < 16; ++i) qo[(size_t)i * HWN] = tv[i] * inv;
    }
}

// ---------------------------------------------------------------------------
extern "C" void kernel_launch(void* const* d_in, const int* in_sizes, int n_in,
                              void* d_out, int out_size, void* d_ws, size_t ws_size,
                              hipStream_t stream) {
    const float* color  = (const float*)d_in[0];
    // d_in[1] = feats: unused by the forward pass
    const float* logits = (const float*)d_in[2];
    const float* wsp    = (const float*)d_in[3];

    float* q_out = (float*)d_out;
    float* kaff  = (float*)d_ws;          // [B,9,HW] f32, 13 MB

    dim3 gridA(HWN / 256, BB);
    affinity_kernel<<<gridA, 256, 0, stream>>>(color, wsp, kaff);

    dim3 gridF(NTILES, BB);               // 2816 tiles x 2 batches
    fused_crf_kernel<<<gridF, 256, 0, stream>>>(logits, kaff, q_out);
}

// Round 13
// 92.301 us; speedup vs baseline: 1.4338x; 1.3472x over previous
//
#include <hip/hip_runtime.h>
#include <hip/hip_fp16.h>

#define HH 256
#define WW 704
#define DD 64
#define CC 3
#define BB 2
#define HWN (HH * WW)       // 180224

#define TY 8                // out-tile rows
#define TX 16               // out-tile cols
#define RY0 12              // q0 region rows (tile + 2*2 halo)
#define RX0 20              // q0 region cols
#define NP0 (RY0 * RX0)     // 240
#define RY1 10              // q1 region rows (tile + 2*1 halo)
#define RX1 18              // q1 region cols
#define NP1 (RY1 * RX1)     // 180
#define NTX (WW / TX)       // 44
#define NTY (HH / TY)       // 32
#define NTILES (NTX * NTY)  // 1408 (divisible by 8 -> bijective XCD swizzle)

static constexpr float INV2Z2 = 1.0f / (2.0f * 1e-3f * 1e-3f);

// ---------------------------------------------------------------------------
// Affinity (r6 version, 1 px/thread — known-good occupancy):
// kaff[b,k,n] = ws * exp(-sum_c (uc-c)^2/(2 zeta^2)); zero-pad semantics.
// ---------------------------------------------------------------------------
__global__ __launch_bounds__(256) void affinity_kernel(
    const float* __restrict__ color, const float* __restrict__ wsp,
    float* __restrict__ kaff)
{
    int n = blockIdx.x * 256 + threadIdx.x;
    int b = blockIdx.y;
    int h = n / WW, w = n - h * WW;
    float wsv = wsp[0];

    const float* cb = color + (size_t)b * CC * HWN + n;
    float c0 = cb[0], c1 = cb[HWN], c2 = cb[2 * HWN];
    bool hm = h > 0, hp = h < HH - 1, wm = w > 0, wp = w < WW - 1;

    float* kb = kaff + (size_t)b * 9 * HWN + n;
#pragma unroll
    for (int dh = -1; dh <= 1; ++dh) {
#pragma unroll
        for (int dw = -1; dw <= 1; ++dw) {
            int k = (dh + 1) * 3 + (dw + 1);
            bool valid = (dh < 0 ? hm : (dh > 0 ? hp : true)) &&
                         (dw < 0 ? wm : (dw > 0 ? wp : true));
            int off = valid ? (dh * WW + dw) : 0;
            float u0 = valid ? cb[off] : 0.f;
            float u1 = valid ? cb[HWN + off] : 0.f;
            float u2 = valid ? cb[2 * HWN + off] : 0.f;
            float d0 = u0 - c0, d1 = u1 - c1, d2 = u2 - c2;
            float ss = d0 * d0 + d1 * d1 + d2 * d2;
            kb[(size_t)k * HWN] = wsv * __expf(-ss * INV2Z2);
        }
    }
}

// ---------------------------------------------------------------------------
// LDS layout: px-major, 32 dwords (64 f16 ch) per px, XOR swizzle on dword
// index: dw(p,q) = p*32 + (q ^ ((p&7)<<2)). Same permutation on store and
// load -> correctness independent of the mixing.
// ---------------------------------------------------------------------------
__device__ __forceinline__ void acc_tap(const unsigned* q, int p0, int cg,
                                        __half2 kh, __half2* tv2) {
    int ia = p0 * 32 + ((cg * 8) ^ ((p0 & 7) << 2));
    int ib = ia ^ 4;
    const __half2* qa = (const __half2*)&q[ia];
    const __half2* qb = (const __half2*)&q[ib];
    tv2[0] = __hfma2(kh, qa[0], tv2[0]);
    tv2[1] = __hfma2(kh, qa[1], tv2[1]);
    tv2[2] = __hfma2(kh, qa[2], tv2[2]);
    tv2[3] = __hfma2(kh, qa[3], tv2[3]);
    tv2[4] = __hfma2(kh, qb[0], tv2[4]);
    tv2[5] = __hfma2(kh, qb[1], tv2[5]);
    tv2[6] = __hfma2(kh, qb[2], tv2[6]);
    tv2[7] = __hfma2(kh, qb[3], tv2[7]);
}

__device__ __forceinline__ void st_px(unsigned* q, int p, int cg,
                                      const float* u, float scale) {
    int ia = p * 32 + ((cg * 8) ^ ((p & 7) << 2));
    int ib = ia ^ 4;
    __half2* qa = (__half2*)&q[ia];
    __half2* qb = (__half2*)&q[ib];
    qa[0] = __floats2half2_rn(u[0]  * scale, u[1]  * scale);
    qa[1] = __floats2half2_rn(u[2]  * scale, u[3]  * scale);
    qa[2] = __floats2half2_rn(u[4]  * scale, u[5]  * scale);
    qa[3] = __floats2half2_rn(u[6]  * scale, u[7]  * scale);
    qb[0] = __floats2half2_rn(u[8]  * scale, u[9]  * scale);
    qb[1] = __floats2half2_rn(u[10] * scale, u[11] * scale);
    qb[2] = __floats2half2_rn(u[12] * scale, u[13] * scale);
    qb[3] = __floats2half2_rn(u[14] * scale, u[15] * scale);
}

// 4-way exclusive prefix + totals over channel-groups (shfl partners at
// pxl+16g share the same task id -> divergence-safe in partial rounds)
__device__ __forceinline__ void scan4(float Aloc, float Bloc, int pxl, int cg,
                                      float& Ar, float& Br, float& T, float& E) {
    float A0 = __shfl(Aloc, pxl),      A1 = __shfl(Aloc, pxl + 16),
          A2 = __shfl(Aloc, pxl + 32), A3 = __shfl(Aloc, pxl + 48);
    float B0 = __shfl(Bloc, pxl),      B1 = __shfl(Bloc, pxl + 16),
          B2 = __shfl(Bloc, pxl + 32), B3 = __shfl(Bloc, pxl + 48);
    T = A0 + A1 + A2 + A3;  E = B0 + B1 + B2 + B3;
    Ar = 0.f; Br = 0.f;
    if (cg > 0) { Ar += A0; Br += B0; }
    if (cg > 1) { Ar += A1; Br += B1; }
    if (cg > 2) { Ar += A2; Br += B2; }
}

// tv[i] = t[e] -> exp(logit - q_hat); returns 1/sum over all 64 ch
// (logits loaded inline as in r6 — keeps register pressure low)
__device__ __forceinline__ float finish_px(float* tv, const float* lg,
                                           int pxl, int cg) {
    float Aloc = 0.f, Bloc = 0.f;
#pragma unroll
    for (int i = 0; i < 16; ++i) {
        float e = (float)(cg * 16 + i);
        Aloc += tv[i]; Bloc += e * tv[i];
    }
    float Ar, Br, T, E;
    scan4(Aloc, Bloc, pxl, cg, Ar, Br, T, E);
    float s = 0.f;
#pragma unroll
    for (int i = 0; i < 16; ++i) {
        float e = (float)(cg * 16 + i);
        Ar += tv[i]; Br += e * tv[i];
        float v = lg[(size_t)i * HWN] - (2.f * (e * Ar - Br) + E - e * T);
        tv[i] = __expf(v); s += tv[i];
    }
    s += __shfl_xor(s, 16);
    s += __shfl_xor(s, 32);
    return 1.f / s;
}

__device__ __forceinline__ void load_k(const float* kfb, int n, int gy, int gx,
                                       float* k) {
#pragma unroll
    for (int j = 0; j < 9; ++j) k[j] = kfb[(size_t)j * HWN + n];
    if (gy <= 0)      { k[0] = k[1] = k[2] = 0.f; }
    if (gy >= HH - 1) { k[6] = k[7] = k[8] = 0.f; }
    if (gx <= 0)      { k[0] = k[3] = k[6] = 0.f; }
    if (gx >= WW - 1) { k[2] = k[5] = k[8] = 0.f; }
}

// 9-tap stencil from an LDS q-region into tv[16] (f32), via packed f16 FMA
__device__ __forceinline__ void stencil9(const unsigned* qs, int rowstride,
                                         int py, int px, int cg,
                                         const float* k, float* tv) {
    __half2 tv2[8];
#pragma unroll
    for (int j = 0; j < 8; ++j) tv2[j] = __float2half2_rn(0.f);
    int base = (py + 1) * rowstride + (px + 1);
#pragma unroll
    for (int tap = 0; tap < 9; ++tap) {
        int dy = tap / 3 - 1, dx = tap - (tap / 3) * 3 - 1;
        acc_tap(qs, base + dy * rowstride + dx, cg, __float2half2_rn(k[tap]), tv2);
    }
#pragma unroll
    for (int j = 0; j < 8; ++j) {
        float2 f = __half22float2(tv2[j]);
        tv[2 * j] = f.x; tv[2 * j + 1] = f.y;
    }
}

// ---------------------------------------------------------------------------
// Fused CRF per 8x16 out-tile (task = 1 px, 4 lanes x 16 ch), 512 threads:
//   P0: q0 = softmax(logits) on 12x20 -> LDS f16   (2 rounds of 128 px)
//   P1: q1 = iter(q0) on 10x18 -> LDS f16          (2 rounds)
//   P2: q2 = iter(q1) on 8x16 -> global            (1 round)
// Same tile/LDS/per-task code as the 98.6 us r6 kernel; 8 waves/block means
// 2 blocks/CU x 8 = 16 waves/CU resident (2x r6) at an implied 4 waves/EU
// target -> VGPR budget 128 >= ~84 live, so no allocator squeeze (r10-r12:
// small-LDS variants squeezed to 48-52 VGPR and spilled ~35 MB).
// ---------------------------------------------------------------------------
__global__ __launch_bounds__(512) void fused_crf_kernel(
    const float* __restrict__ logits, const float* __restrict__ kaff,
    float* __restrict__ qout)
{
    __shared__ unsigned q0s[NP0 * 32];   // 30,720 B
    __shared__ unsigned q1s[NP1 * 32];   // 23,040 B

    const int t = threadIdx.x;
    const int lane = t & 63;
    const int wv = t >> 6;          // 0..7
    const int pxl = lane & 15;
    const int cg = lane >> 4;       // channels [16cg, 16cg+16)
    const int b = blockIdx.y;

    const int bid = blockIdx.x;     // XCD swizzle (1408 % 8 == 0 -> bijective)
    const int pb = (bid & 7) * (NTILES / 8) + (bid >> 3);
    const int tyr = pb / NTX, txc = pb - tyr * NTX;
    const int y0 = tyr * TY, x0 = txc * TX;

    const float* lgb = logits + ((size_t)b * DD + cg * 16) * HWN;
    const float* kfb = kaff + (size_t)b * 9 * HWN;

    // ---------------- P0: q0 = softmax(logits) on 12x20 ----------------
    for (int r = 0; r < 2; ++r) {
        int id = r * 128 + wv * 16 + pxl;
        if (id < NP0) {
            int py = id / RX0, px = id - py * RX0;
            int gy = min(max(y0 - 2 + py, 0), HH - 1);
            int gx = min(max(x0 - 2 + px, 0), WW - 1);
            const float* lg = lgb + gy * WW + gx;
            float v[16];
            float s = 0.f;
#pragma unroll
            for (int i = 0; i < 16; ++i) {
                v[i] = __expf(lg[(size_t)i * HWN]);
                s += v[i];
            }
            s += __shfl_xor(s, 16);
            s += __shfl_xor(s, 32);
            st_px(q0s, id, cg, v, 1.0f / s);
        }
    }
    __syncthreads();

    // ---------------- P1: q1 = iter(q0) on 10x18 ----------------
    for (int r = 0; r < 2; ++r) {
        int id = r * 128 + wv * 16 + pxl;
        if (id < NP1) {
            int py = id / RX1, px = id - py * RX1;
            int gy = y0 - 1 + py, gx = x0 - 1 + px;   // may be out of image
            int cy = min(max(gy, 0), HH - 1), cx = min(max(gx, 0), WW - 1);
            int n = cy * WW + cx;

            float k[9];
            load_k(kfb, n, gy, gx, k);

            float tv[16];
            stencil9(q0s, RX0, py, px, cg, k, tv);
            float inv = finish_px(tv, lgb + n, pxl, cg);
            st_px(q1s, id, cg, tv, inv);
        }
    }
    __syncthreads();

    // ---------------- P2: q2 = iter(q1) -> global, 8x16 ----------------
    {
        int id = wv * 16 + pxl;              // 0..127, exactly the tile
        int py = id >> 4, px = id & 15;
        int gy = y0 + py, gx = x0 + px;      // always in image
        int n = gy * WW + gx;

        float k[9];
        load_k(kfb, n, gy, gx, k);

        float tv[16];
        stencil9(q1s, RX1, py, px, cg, k, tv);
        float inv = finish_px(tv, lgb + n, pxl, cg);

        float* qo = qout + ((size_t)b * DD + cg * 16) * HWN + n;
#pragma unroll
        for (int i = 0; i < 16; ++i) qo[(size_t)i * HWN] = tv[i] * inv;
    }
}

// ---------------------------------------------------------------------------
extern "C" void kernel_launch(void* const* d_in, const int* in_sizes, int n_in,
                              void* d_out, int out_size, void* d_ws, size_t ws_size,
                              hipStream_t stream) {
    const float* color  = (const float*)d_in[0];
    // d_in[1] = feats: unused by the forward pass
    const float* logits = (const float*)d_in[2];
    const float* wsp    = (const float*)d_in[3];

    float* q_out = (float*)d_out;
    float* kaff  = (float*)d_ws;          // [B,9,HW] f32, 13 MB

    dim3 gridA(HWN / 256, BB);
    affinity_kernel<<<gridA, 256, 0, stream>>>(color, wsp, kaff);

    dim3 gridF(NTILES, BB);               // 1408 tiles x 2 batches
    fused_crf_kernel<<<gridF, 512, 0, stream>>>(logits, kaff, q_out);
}

// Round 14
// 91.491 us; speedup vs baseline: 1.4465x; 1.0088x over previous
//
#include <hip/hip_runtime.h>
#include <hip/hip_fp16.h>

#define HH 256
#define WW 704
#define DD 64
#define CC 3
#define BB 2
#define HWN (HH * WW)       // 180224

#define TY 8                // out-tile rows
#define TX 16               // out-tile cols
#define RY0 12              // q0 region rows (tile + 2*2 halo)
#define RX0 20              // q0 region cols
#define NP0 (RY0 * RX0)     // 240
#define RY1 10              // q1 region rows (tile + 2*1 halo)
#define RX1 18              // q1 region cols
#define NP1 (RY1 * RX1)     // 180
#define NTX (WW / TX)       // 44
#define NTY (HH / TY)       // 32
#define NTILES (NTX * NTY)  // 1408 (divisible by 8 -> bijective XCD swizzle)

static constexpr float INV2Z2 = 1.0f / (2.0f * 1e-3f * 1e-3f);

// ---------------------------------------------------------------------------
// Affinity (r6 version, 1 px/thread — known-good occupancy):
// kaff[b,k,n] = ws * exp(-sum_c (uc-c)^2/(2 zeta^2)); zero-pad semantics.
// ---------------------------------------------------------------------------
__global__ __launch_bounds__(256) void affinity_kernel(
    const float* __restrict__ color, const float* __restrict__ wsp,
    float* __restrict__ kaff)
{
    int n = blockIdx.x * 256 + threadIdx.x;
    int b = blockIdx.y;
    int h = n / WW, w = n - h * WW;
    float wsv = wsp[0];

    const float* cb = color + (size_t)b * CC * HWN + n;
    float c0 = cb[0], c1 = cb[HWN], c2 = cb[2 * HWN];
    bool hm = h > 0, hp = h < HH - 1, wm = w > 0, wp = w < WW - 1;

    float* kb = kaff + (size_t)b * 9 * HWN + n;
#pragma unroll
    for (int dh = -1; dh <= 1; ++dh) {
#pragma unroll
        for (int dw = -1; dw <= 1; ++dw) {
            int k = (dh + 1) * 3 + (dw + 1);
            bool valid = (dh < 0 ? hm : (dh > 0 ? hp : true)) &&
                         (dw < 0 ? wm : (dw > 0 ? wp : true));
            int off = valid ? (dh * WW + dw) : 0;
            float u0 = valid ? cb[off] : 0.f;
            float u1 = valid ? cb[HWN + off] : 0.f;
            float u2 = valid ? cb[2 * HWN + off] : 0.f;
            float d0 = u0 - c0, d1 = u1 - c1, d2 = u2 - c2;
            float ss = d0 * d0 + d1 * d1 + d2 * d2;
            kb[(size_t)k * HWN] = wsv * __expf(-ss * INV2Z2);
        }
    }
}

// ---------------------------------------------------------------------------
// LDS layout: px-major, 32 dwords (64 f16 ch) per px, XOR swizzle on dword
// index: dw(p,q) = p*32 + (q ^ ((p&7)<<2)). Same permutation on store and
// load -> correctness independent of the mixing.
// ---------------------------------------------------------------------------
__device__ __forceinline__ void acc_tap(const unsigned* q, int p0, int cg,
                                        __half2 kh, __half2* tv2) {
    int ia = p0 * 32 + ((cg * 8) ^ ((p0 & 7) << 2));
    int ib = ia ^ 4;
    const __half2* qa = (const __half2*)&q[ia];
    const __half2* qb = (const __half2*)&q[ib];
    tv2[0] = __hfma2(kh, qa[0], tv2[0]);
    tv2[1] = __hfma2(kh, qa[1], tv2[1]);
    tv2[2] = __hfma2(kh, qa[2], tv2[2]);
    tv2[3] = __hfma2(kh, qa[3], tv2[3]);
    tv2[4] = __hfma2(kh, qb[0], tv2[4]);
    tv2[5] = __hfma2(kh, qb[1], tv2[5]);
    tv2[6] = __hfma2(kh, qb[2], tv2[6]);
    tv2[7] = __hfma2(kh, qb[3], tv2[7]);
}

__device__ __forceinline__ void st_px(unsigned* q, int p, int cg,
                                      const float* u, float scale) {
    int ia = p * 32 + ((cg * 8) ^ ((p & 7) << 2));
    int ib = ia ^ 4;
    __half2* qa = (__half2*)&q[ia];
    __half2* qb = (__half2*)&q[ib];
    qa[0] = __floats2half2_rn(u[0]  * scale, u[1]  * scale);
    qa[1] = __floats2half2_rn(u[2]  * scale, u[3]  * scale);
    qa[2] = __floats2half2_rn(u[4]  * scale, u[5]  * scale);
    qa[3] = __floats2half2_rn(u[6]  * scale, u[7]  * scale);
    qb[0] = __floats2half2_rn(u[8]  * scale, u[9]  * scale);
    qb[1] = __floats2half2_rn(u[10] * scale, u[11] * scale);
    qb[2] = __floats2half2_rn(u[12] * scale, u[13] * scale);
    qb[3] = __floats2half2_rn(u[14] * scale, u[15] * scale);
}

// 4-way exclusive prefix + totals over channel-groups (shfl partners at
// pxl+16g share the same task id -> divergence-safe in partial rounds)
__device__ __forceinline__ void scan4(float Aloc, float Bloc, int pxl, int cg,
                                      float& Ar, float& Br, float& T, float& E) {
    float A0 = __shfl(Aloc, pxl),      A1 = __shfl(Aloc, pxl + 16),
          A2 = __shfl(Aloc, pxl + 32), A3 = __shfl(Aloc, pxl + 48);
    float B0 = __shfl(Bloc, pxl),      B1 = __shfl(Bloc, pxl + 16),
          B2 = __shfl(Bloc, pxl + 32), B3 = __shfl(Bloc, pxl + 48);
    T = A0 + A1 + A2 + A3;  E = B0 + B1 + B2 + B3;
    Ar = 0.f; Br = 0.f;
    if (cg > 0) { Ar += A0; Br += B0; }
    if (cg > 1) { Ar += A1; Br += B1; }
    if (cg > 2) { Ar += A2; Br += B2; }
}

// tv[i] = t[e] -> exp(logit - q_hat); returns 1/sum over all 64 ch
__device__ __forceinline__ float finish_px(float* tv, const float* lg,
                                           int pxl, int cg) {
    float Aloc = 0.f, Bloc = 0.f;
#pragma unroll
    for (int i = 0; i < 16; ++i) {
        float e = (float)(cg * 16 + i);
        Aloc += tv[i]; Bloc += e * tv[i];
    }
    float Ar, Br, T, E;
    scan4(Aloc, Bloc, pxl, cg, Ar, Br, T, E);
    float s = 0.f;
#pragma unroll
    for (int i = 0; i < 16; ++i) {
        float e = (float)(cg * 16 + i);
        Ar += tv[i]; Br += e * tv[i];
        float v = lg[(size_t)i * HWN] - (2.f * (e * Ar - Br) + E - e * T);
        tv[i] = __expf(v); s += tv[i];
    }
    s += __shfl_xor(s, 16);
    s += __shfl_xor(s, 32);
    return 1.f / s;
}

__device__ __forceinline__ void load_k(const float* kfb, int n, int gy, int gx,
                                       float* k) {
#pragma unroll
    for (int j = 0; j < 9; ++j) k[j] = kfb[(size_t)j * HWN + n];
    if (gy <= 0)      { k[0] = k[1] = k[2] = 0.f; }
    if (gy >= HH - 1) { k[6] = k[7] = k[8] = 0.f; }
    if (gx <= 0)      { k[0] = k[3] = k[6] = 0.f; }
    if (gx >= WW - 1) { k[2] = k[5] = k[8] = 0.f; }
}

// 9-tap stencil from an LDS q-region into tv[16] (f32), via packed f16 FMA
__device__ __forceinline__ void stencil9(const unsigned* qs, int rowstride,
                                         int py, int px, int cg,
                                         const float* k, float* tv) {
    __half2 tv2[8];
#pragma unroll
    for (int j = 0; j < 8; ++j) tv2[j] = __float2half2_rn(0.f);
    int base = (py + 1) * rowstride + (px + 1);
#pragma unroll
    for (int tap = 0; tap < 9; ++tap) {
        int dy = tap / 3 - 1, dx = tap - (tap / 3) * 3 - 1;
        acc_tap(qs, base + dy * rowstride + dx, cg, __float2half2_rn(k[tap]), tv2);
    }
#pragma unroll
    for (int j = 0; j < 8; ++j) {
        float2 f = __half22float2(tv2[j]);
        tv[2 * j] = f.x; tv[2 * j + 1] = f.y;
    }
}

// ---------------------------------------------------------------------------
// Fused CRF per 8x16 out-tile (task = 1 px, 4 lanes x 16 ch), 512 threads.
//   P0: q0 = softmax(logits) on 12x20 -> LDS f16   (2 rounds of 128 px)
//   P1: q1 = iter(q0) on 10x18 -> LDS f16          (round A full, round B partial)
//   P2: q2 = iter(q1) on 8x16 -> global            (1 round)
// r13 + cross-barrier kaff prefetch: P1's k[9] (both rounds) are loaded
// BEFORE the first __syncthreads and P2's k[9] before the second, so the
// compiler's vmcnt(0) barrier drain completes them during the barrier wait
// instead of stalling the next phase's start. kaff is read-only -> safe.
// ---------------------------------------------------------------------------
__global__ __launch_bounds__(512) void fused_crf_kernel(
    const float* __restrict__ logits, const float* __restrict__ kaff,
    float* __restrict__ qout)
{
    __shared__ unsigned q0s[NP0 * 32];   // 30,720 B
    __shared__ unsigned q1s[NP1 * 32];   // 23,040 B

    const int t = threadIdx.x;
    const int lane = t & 63;
    const int wv = t >> 6;          // 0..7
    const int pxl = lane & 15;
    const int cg = lane >> 4;       // channels [16cg, 16cg+16)
    const int b = blockIdx.y;
    const int tid16 = wv * 16 + pxl;  // 0..127

    const int bid = blockIdx.x;     // XCD swizzle (1408 % 8 == 0 -> bijective)
    const int pb = (bid & 7) * (NTILES / 8) + (bid >> 3);
    const int tyr = pb / NTX, txc = pb - tyr * NTX;
    const int y0 = tyr * TY, x0 = txc * TX;

    const float* lgb = logits + ((size_t)b * DD + cg * 16) * HWN;
    const float* kfb = kaff + (size_t)b * 9 * HWN;

    // ---------------- P0: q0 = softmax(logits) on 12x20 ----------------
    for (int r = 0; r < 2; ++r) {
        int id = r * 128 + tid16;
        if (id < NP0) {
            int py = id / RX0, px = id - py * RX0;
            int gy = min(max(y0 - 2 + py, 0), HH - 1);
            int gx = min(max(x0 - 2 + px, 0), WW - 1);
            const float* lg = lgb + gy * WW + gx;
            float v[16];
            float s = 0.f;
#pragma unroll
            for (int i = 0; i < 16; ++i) {
                v[i] = __expf(lg[(size_t)i * HWN]);
                s += v[i];
            }
            s += __shfl_xor(s, 16);
            s += __shfl_xor(s, 32);
            st_px(q0s, id, cg, v, 1.0f / s);
        }
    }

    // ---- prefetch P1 kaff (rounds A and B) before the barrier ----
    // round A: id = tid16 (0..127, always < NP1)
    const int pyA = tid16 / RX1, pxA = tid16 - pyA * RX1;
    const int gyA = y0 - 1 + pyA, gxA = x0 - 1 + pxA;
    const int cyA = min(max(gyA, 0), HH - 1), cxA = min(max(gxA, 0), WW - 1);
    const int nA = cyA * WW + cxA;
    float kA[9];
    load_k(kfb, nA, gyA, gxA, kA);
    // round B: id = 128 + tid16, valid iff < NP1 (clamped for address calc)
    const int idB = 128 + tid16;
    const int idBc = min(idB, NP1 - 1);
    const int pyB = idBc / RX1, pxB = idBc - pyB * RX1;
    const int gyB = y0 - 1 + pyB, gxB = x0 - 1 + pxB;
    const int cyB = min(max(gyB, 0), HH - 1), cxB = min(max(gxB, 0), WW - 1);
    const int nB = cyB * WW + cxB;
    float kB[9];
    load_k(kfb, nB, gyB, gxB, kB);

    __syncthreads();

    // ---------------- P1: q1 = iter(q0) on 10x18 ----------------
    {   // round A (all lanes valid)
        float tv[16];
        stencil9(q0s, RX0, pyA, pxA, cg, kA, tv);
        float inv = finish_px(tv, lgb + nA, pxl, cg);
        st_px(q1s, tid16, cg, tv, inv);
    }
    if (idB < NP1) {   // round B (partial; shfl partners share id -> safe)
        float tv[16];
        stencil9(q0s, RX0, pyB, pxB, cg, kB, tv);
        float inv = finish_px(tv, lgb + nB, pxl, cg);
        st_px(q1s, idB, cg, tv, inv);
    }

    // ---- prefetch P2 kaff before the barrier ----
    const int py2 = tid16 >> 4, px2 = tid16 & 15;
    const int gy2 = y0 + py2, gx2 = x0 + px2;    // always in image
    const int n2 = gy2 * WW + gx2;
    float k2[9];
    load_k(kfb, n2, gy2, gx2, k2);

    __syncthreads();

    // ---------------- P2: q2 = iter(q1) -> global, 8x16 ----------------
    {
        float tv[16];
        stencil9(q1s, RX1, py2, px2, cg, k2, tv);
        float inv = finish_px(tv, lgb + n2, pxl, cg);

        float* qo = qout + ((size_t)b * DD + cg * 16) * HWN + n2;
#pragma unroll
        for (int i = 0; i < 16; ++i) qo[(size_t)i * HWN] = tv[i] * inv;
    }
}

// ---------------------------------------------------------------------------
extern "C" void kernel_launch(void* const* d_in, const int* in_sizes, int n_in,
                              void* d_out, int out_size, void* d_ws, size_t ws_size,
                              hipStream_t stream) {
    const float* color  = (const float*)d_in[0];
    // d_in[1] = feats: unused by the forward pass
    const float* logits = (const float*)d_in[2];
    const float* wsp    = (const float*)d_in[3];

    float* q_out = (float*)d_out;
    float* kaff  = (float*)d_ws;          // [B,9,HW] f32, 13 MB

    dim3 gridA(HWN / 256, BB);
    affinity_kernel<<<gridA, 256, 0, stream>>>(color, wsp, kaff);

    dim3 gridF(NTILES, BB);               // 1408 tiles x 2 batches
    fused_crf_kernel<<<gridF, 512, 0, stream>>>(logits, kaff, q_out);
}

// Round 15
// 90.012 us; speedup vs baseline: 1.4702x; 1.0164x over previous
//
#include <hip/hip_runtime.h>
#include <hip/hip_fp16.h>

#define HH 256
#define WW 704
#define DD 64
#define CC 3
#define BB 2
#define HWN (HH * WW)       // 180224

#define TY 8                // out-tile rows
#define TX 16               // out-tile cols
#define RY0 12              // q0 region rows (tile + 2*2 halo)
#define RX0 20              // q0 region cols
#define NP0 (RY0 * RX0)     // 240
#define RY1 10              // q1 region rows (tile + 2*1 halo)
#define RX1 18              // q1 region cols
#define NP1 (RY1 * RX1)     // 180
#define NTX (WW / TX)       // 44
#define NTY (HH / TY)       // 32
#define NTILES (NTX * NTY)  // 1408 (divisible by 8 -> bijective XCD swizzle)

static constexpr float INV2Z2 = 1.0f / (2.0f * 1e-3f * 1e-3f);

// ---------------------------------------------------------------------------
// Affinity: kaff[b,k,n] = ws * exp(-sum_c (uc-c)^2/(2 zeta^2)); zero-pad.
// ---------------------------------------------------------------------------
__global__ __launch_bounds__(256) void affinity_kernel(
    const float* __restrict__ color, const float* __restrict__ wsp,
    float* __restrict__ kaff)
{
    int n = blockIdx.x * 256 + threadIdx.x;
    int b = blockIdx.y;
    int h = n / WW, w = n - h * WW;
    float wsv = wsp[0];

    const float* cb = color + (size_t)b * CC * HWN + n;
    float c0 = cb[0], c1 = cb[HWN], c2 = cb[2 * HWN];
    bool hm = h > 0, hp = h < HH - 1, wm = w > 0, wp = w < WW - 1;

    float* kb = kaff + (size_t)b * 9 * HWN + n;
#pragma unroll
    for (int dh = -1; dh <= 1; ++dh) {
#pragma unroll
        for (int dw = -1; dw <= 1; ++dw) {
            int k = (dh + 1) * 3 + (dw + 1);
            bool valid = (dh < 0 ? hm : (dh > 0 ? hp : true)) &&
                         (dw < 0 ? wm : (dw > 0 ? wp : true));
            int off = valid ? (dh * WW + dw) : 0;
            float u0 = valid ? cb[off] : 0.f;
            float u1 = valid ? cb[HWN + off] : 0.f;
            float u2 = valid ? cb[2 * HWN + off] : 0.f;
            float d0 = u0 - c0, d1 = u1 - c1, d2 = u2 - c2;
            float ss = d0 * d0 + d1 * d1 + d2 * d2;
            kb[(size_t)k * HWN] = wsv * __expf(-ss * INV2Z2);
        }
    }
}

// ---------------------------------------------------------------------------
// LDS layout: px-major, 32 dwords (64 f16 ch) per px, XOR swizzle on dword
// index: dw(p,q) = p*32 + (q ^ ((p&7)<<2)). Same permutation on store and
// load -> correctness independent of the mixing.
// ---------------------------------------------------------------------------
__device__ __forceinline__ void acc_tap(const unsigned* q, int p0, int cg,
                                        __half2 kh, __half2* tv2) {
    int ia = p0 * 32 + ((cg * 8) ^ ((p0 & 7) << 2));
    int ib = ia ^ 4;
    const __half2* qa = (const __half2*)&q[ia];
    const __half2* qb = (const __half2*)&q[ib];
    tv2[0] = __hfma2(kh, qa[0], tv2[0]);
    tv2[1] = __hfma2(kh, qa[1], tv2[1]);
    tv2[2] = __hfma2(kh, qa[2], tv2[2]);
    tv2[3] = __hfma2(kh, qa[3], tv2[3]);
    tv2[4] = __hfma2(kh, qb[0], tv2[4]);
    tv2[5] = __hfma2(kh, qb[1], tv2[5]);
    tv2[6] = __hfma2(kh, qb[2], tv2[6]);
    tv2[7] = __hfma2(kh, qb[3], tv2[7]);
}

// pack 16 scaled channels into two uint4 (8 x half2)
__device__ __forceinline__ void pack_px(const float* u, float scale,
                                        uint4& a, uint4& bu) {
    __half2* pa = (__half2*)&a;
    __half2* pb = (__half2*)&bu;
    pa[0] = __floats2half2_rn(u[0]  * scale, u[1]  * scale);
    pa[1] = __floats2half2_rn(u[2]  * scale, u[3]  * scale);
    pa[2] = __floats2half2_rn(u[4]  * scale, u[5]  * scale);
    pa[3] = __floats2half2_rn(u[6]  * scale, u[7]  * scale);
    pb[0] = __floats2half2_rn(u[8]  * scale, u[9]  * scale);
    pb[1] = __floats2half2_rn(u[10] * scale, u[11] * scale);
    pb[2] = __floats2half2_rn(u[12] * scale, u[13] * scale);
    pb[3] = __floats2half2_rn(u[14] * scale, u[15] * scale);
}

__device__ __forceinline__ void st_raw(unsigned* q, int p, int cg,
                                       uint4 a, uint4 bu) {
    int ia = p * 32 + ((cg * 8) ^ ((p & 7) << 2));
    *(uint4*)&q[ia] = a;
    *(uint4*)&q[ia ^ 4] = bu;
}

__device__ __forceinline__ void st_px(unsigned* q, int p, int cg,
                                      const float* u, float scale) {
    uint4 a, bu;
    pack_px(u, scale, a, bu);
    st_raw(q, p, cg, a, bu);
}

// 4-way exclusive prefix + totals over channel-groups (shfl partners at
// pxl+16g share the same task id -> divergence-safe in partial rounds)
__device__ __forceinline__ void scan4(float Aloc, float Bloc, int pxl, int cg,
                                      float& Ar, float& Br, float& T, float& E) {
    float A0 = __shfl(Aloc, pxl),      A1 = __shfl(Aloc, pxl + 16),
          A2 = __shfl(Aloc, pxl + 32), A3 = __shfl(Aloc, pxl + 48);
    float B0 = __shfl(Bloc, pxl),      B1 = __shfl(Bloc, pxl + 16),
          B2 = __shfl(Bloc, pxl + 32), B3 = __shfl(Bloc, pxl + 48);
    T = A0 + A1 + A2 + A3;  E = B0 + B1 + B2 + B3;
    Ar = 0.f; Br = 0.f;
    if (cg > 0) { Ar += A0; Br += B0; }
    if (cg > 1) { Ar += A1; Br += B1; }
    if (cg > 2) { Ar += A2; Br += B2; }
}

// tv[i] = t[e] -> exp(logit - q_hat); returns 1/sum over all 64 ch
__device__ __forceinline__ float finish_px(float* tv, const float* lg,
                                           int pxl, int cg) {
    float Aloc = 0.f, Bloc = 0.f;
#pragma unroll
    for (int i = 0; i < 16; ++i) {
        float e = (float)(cg * 16 + i);
        Aloc += tv[i]; Bloc += e * tv[i];
    }
    float Ar, Br, T, E;
    scan4(Aloc, Bloc, pxl, cg, Ar, Br, T, E);
    float s = 0.f;
#pragma unroll
    for (int i = 0; i < 16; ++i) {
        float e = (float)(cg * 16 + i);
        Ar += tv[i]; Br += e * tv[i];
        float v = lg[(size_t)i * HWN] - (2.f * (e * Ar - Br) + E - e * T);
        tv[i] = __expf(v); s += tv[i];
    }
    s += __shfl_xor(s, 16);
    s += __shfl_xor(s, 32);
    return 1.f / s;
}

__device__ __forceinline__ void load_k(const float* kfb, int n, int gy, int gx,
                                       float* k) {
#pragma unroll
    for (int j = 0; j < 9; ++j) k[j] = kfb[(size_t)j * HWN + n];
    if (gy <= 0)      { k[0] = k[1] = k[2] = 0.f; }
    if (gy >= HH - 1) { k[6] = k[7] = k[8] = 0.f; }
    if (gx <= 0)      { k[0] = k[3] = k[6] = 0.f; }
    if (gx >= WW - 1) { k[2] = k[5] = k[8] = 0.f; }
}

// 9-tap stencil from an LDS q-region into tv[16] (f32), via packed f16 FMA
__device__ __forceinline__ void stencil9(const unsigned* qs, int rowstride,
                                         int py, int px, int cg,
                                         const float* k, float* tv) {
    __half2 tv2[8];
#pragma unroll
    for (int j = 0; j < 8; ++j) tv2[j] = __float2half2_rn(0.f);
    int base = (py + 1) * rowstride + (px + 1);
#pragma unroll
    for (int tap = 0; tap < 9; ++tap) {
        int dy = tap / 3 - 1, dx = tap - (tap / 3) * 3 - 1;
        acc_tap(qs, base + dy * rowstride + dx, cg, __float2half2_rn(k[tap]), tv2);
    }
#pragma unroll
    for (int j = 0; j < 8; ++j) {
        float2 f = __half22float2(tv2[j]);
        tv[2 * j] = f.x; tv[2 * j + 1] = f.y;
    }
}

// ---------------------------------------------------------------------------
// Fused CRF per 8x16 out-tile (task = 1 px, 4 lanes x 16 ch), 512 threads.
// Single aliased LDS buffer (30.7 KB): holds q0 during P0/P1, then q1.
//   P0: q0 = softmax(logits) on 12x20 -> LDS
//   P1: compute q1 on 10x18 into REGISTERS (reads q0)   [barrier]
//       store q1 packed-f16 into the same LDS buffer    [barrier]
//   P2: q2 = iter(q1) on 8x16 -> global
// Halving LDS (53.8 -> 30.7 KB) lifts the 2-blocks/CU residency cap that
// kept r13 latency-bound at ~43% occupancy; VGPR ~64 still allows 32 waves.
// ---------------------------------------------------------------------------
__global__ __launch_bounds__(512) void fused_crf_kernel(
    const float* __restrict__ logits, const float* __restrict__ kaff,
    float* __restrict__ qout)
{
    __shared__ unsigned qs[NP0 * 32];   // 30,720 B (q0, later q1)

    const int t = threadIdx.x;
    const int lane = t & 63;
    const int wv = t >> 6;          // 0..7
    const int pxl = lane & 15;
    const int cg = lane >> 4;       // channels [16cg, 16cg+16)
    const int b = blockIdx.y;
    const int tid16 = wv * 16 + pxl;  // 0..127

    const int bid = blockIdx.x;     // XCD swizzle (1408 % 8 == 0 -> bijective)
    const int pb = (bid & 7) * (NTILES / 8) + (bid >> 3);
    const int tyr = pb / NTX, txc = pb - tyr * NTX;
    const int y0 = tyr * TY, x0 = txc * TX;

    const float* lgb = logits + ((size_t)b * DD + cg * 16) * HWN;
    const float* kfb = kaff + (size_t)b * 9 * HWN;

    // ---------------- P0: q0 = softmax(logits) on 12x20 ----------------
    for (int r = 0; r < 2; ++r) {
        int id = r * 128 + tid16;
        if (id < NP0) {
            int py = id / RX0, px = id - py * RX0;
            int gy = min(max(y0 - 2 + py, 0), HH - 1);
            int gx = min(max(x0 - 2 + px, 0), WW - 1);
            const float* lg = lgb + gy * WW + gx;
            float v[16];
            float s = 0.f;
#pragma unroll
            for (int i = 0; i < 16; ++i) {
                v[i] = __expf(lg[(size_t)i * HWN]);
                s += v[i];
            }
            s += __shfl_xor(s, 16);
            s += __shfl_xor(s, 32);
            st_px(qs, id, cg, v, 1.0f / s);
        }
    }
    __syncthreads();

    // ---------------- P1: q1 = iter(q0) on 10x18, results in regs ----------
    uint4 aA, buA;
    {   // round A: id = tid16 (0..127, always < NP1)
        int py = tid16 / RX1, px = tid16 - py * RX1;
        int gy = y0 - 1 + py, gx = x0 - 1 + px;
        int cy = min(max(gy, 0), HH - 1), cx = min(max(gx, 0), WW - 1);
        int n = cy * WW + cx;
        float k[9];
        load_k(kfb, n, gy, gx, k);
        float tv[16];
        stencil9(qs, RX0, py, px, cg, k, tv);
        float inv = finish_px(tv, lgb + n, pxl, cg);
        pack_px(tv, inv, aA, buA);
    }
    const int idB = 128 + tid16;
    const bool validB = idB < NP1;
    uint4 aB, buB;
    if (validB) {   // round B partial; shfl partners share id -> safe
        int py = idB / RX1, px = idB - py * RX1;
        int gy = y0 - 1 + py, gx = x0 - 1 + px;
        int cy = min(max(gy, 0), HH - 1), cx = min(max(gx, 0), WW - 1);
        int n = cy * WW + cx;
        float k[9];
        load_k(kfb, n, gy, gx, k);
        float tv[16];
        stencil9(qs, RX0, py, px, cg, k, tv);
        float inv = finish_px(tv, lgb + n, pxl, cg);
        pack_px(tv, inv, aB, buB);
    }
    __syncthreads();   // all q0 reads complete -> buffer reusable

    st_raw(qs, tid16, cg, aA, buA);
    if (validB) st_raw(qs, idB, cg, aB, buB);
    __syncthreads();   // q1 fully written

    // ---------------- P2: q2 = iter(q1) -> global, 8x16 ----------------
    {
        int py = tid16 >> 4, px = tid16 & 15;
        int gy = y0 + py, gx = x0 + px;      // always in image
        int n = gy * WW + gx;

        float k[9];
        load_k(kfb, n, gy, gx, k);

        float tv[16];
        stencil9(qs, RX1, py, px, cg, k, tv);
        float inv = finish_px(tv, lgb + n, pxl, cg);

        float* qo = qout + ((size_t)b * DD + cg * 16) * HWN + n;
#pragma unroll
        for (int i = 0; i < 16; ++i) qo[(size_t)i * HWN] = tv[i] * inv;
    }
}

// ---------------------------------------------------------------------------
extern "C" void kernel_launch(void* const* d_in, const int* in_sizes, int n_in,
                              void* d_out, int out_size, void* d_ws, size_t ws_size,
                              hipStream_t stream) {
    const float* color  = (const float*)d_in[0];
    // d_in[1] = feats: unused by the forward pass
    const float* logits = (const float*)d_in[2];
    const float* wsp    = (const float*)d_in[3];

    float* q_out = (float*)d_out;
    float* kaff  = (float*)d_ws;          // [B,9,HW] f32, 13 MB

    dim3 gridA(HWN / 256, BB);
    affinity_kernel<<<gridA, 256, 0, stream>>>(color, wsp, kaff);

    dim3 gridF(NTILES, BB);               // 1408 tiles x 2 batches
    fused_crf_kernel<<<gridF, 512, 0, stream>>>(logits, kaff, q_out);
}

// Round 17
// 80.374 us; speedup vs baseline: 1.6465x; 1.1199x over previous
//
#include <hip/hip_runtime.h>
#include <hip/hip_fp16.h>

#define HH 256
#define WW 704
#define DD 64
#define CC 3
#define BB 2
#define HWN (HH * WW)       // 180224

#define TY 8                // out-tile rows
#define TX 16               // out-tile cols
#define RY0 12              // q0 region rows (tile + 2*2 halo)
#define RX0 20              // q0 region cols
#define NP0 (RY0 * RX0)     // 240
#define RY1 10              // q1 region rows (tile + 2*1 halo)
#define RX1 18              // q1 region cols
#define NP1 (RY1 * RX1)     // 180
#define NTX (WW / TX)       // 44
#define NTY (HH / TY)       // 32
#define NTILES (NTX * NTY)  // 1408 (divisible by 8 -> bijective XCD swizzle)

static constexpr float INV2Z2 = 1.0f / (2.0f * 1e-3f * 1e-3f);
static constexpr float LOG2E  = 1.4426950408889634f;

__device__ __forceinline__ float fexp2(float x) {
#if __has_builtin(__builtin_amdgcn_exp2f)
    return __builtin_amdgcn_exp2f(x);
#else
    return __expf(x * 0.6931471805599453f);
#endif
}

// ---------------------------------------------------------------------------
// Affinity: kaff[b,k,n] = LOG2E * ws * exp(-sum_c (uc-c)^2/(2 zeta^2)).
// log2e pre-scale -> the CRF prefix sums yield q_hat*log2e, so the exp in the
// iteration is a raw v_exp_f32 (2^-x). Zero-pad semantics.
// ---------------------------------------------------------------------------
__global__ __launch_bounds__(256) void affinity_kernel(
    const float* __restrict__ color, const float* __restrict__ wsp,
    float* __restrict__ kaff)
{
    int n = blockIdx.x * 256 + threadIdx.x;
    int b = blockIdx.y;
    int h = n / WW, w = n - h * WW;
    float wsv = wsp[0] * LOG2E;

    const float* cb = color + (size_t)b * CC * HWN + n;
    float c0 = cb[0], c1 = cb[HWN], c2 = cb[2 * HWN];
    bool hm = h > 0, hp = h < HH - 1, wm = w > 0, wp = w < WW - 1;

    float* kb = kaff + (size_t)b * 9 * HWN + n;
#pragma unroll
    for (int dh = -1; dh <= 1; ++dh) {
#pragma unroll
        for (int dw = -1; dw <= 1; ++dw) {
            int k = (dh + 1) * 3 + (dw + 1);
            bool valid = (dh < 0 ? hm : (dh > 0 ? hp : true)) &&
                         (dw < 0 ? wm : (dw > 0 ? wp : true));
            int off = valid ? (dh * WW + dw) : 0;
            float u0 = valid ? cb[off] : 0.f;
            float u1 = valid ? cb[HWN + off] : 0.f;
            float u2 = valid ? cb[2 * HWN + off] : 0.f;
            float d0 = u0 - c0, d1 = u1 - c1, d2 = u2 - c2;
            float ss = d0 * d0 + d1 * d1 + d2 * d2;
            kb[(size_t)k * HWN] = wsv * __expf(-ss * INV2Z2);
        }
    }
}

// ---------------------------------------------------------------------------
// LDS layout: px-major, 32 dwords (64 f16 ch) per px, XOR swizzle on dword
// index: dw(p,q) = p*32 + (q ^ ((p&7)<<2)). Same permutation on store and
// load -> correctness independent of the mixing.
// ---------------------------------------------------------------------------
__device__ __forceinline__ void acc_tap(const unsigned* q, int p0, int cg,
                                        __half2 kh, __half2* tv2) {
    int ia = p0 * 32 + ((cg * 8) ^ ((p0 & 7) << 2));
    int ib = ia ^ 4;
    const __half2* qa = (const __half2*)&q[ia];
    const __half2* qb = (const __half2*)&q[ib];
    tv2[0] = __hfma2(kh, qa[0], tv2[0]);
    tv2[1] = __hfma2(kh, qa[1], tv2[1]);
    tv2[2] = __hfma2(kh, qa[2], tv2[2]);
    tv2[3] = __hfma2(kh, qa[3], tv2[3]);
    tv2[4] = __hfma2(kh, qb[0], tv2[4]);
    tv2[5] = __hfma2(kh, qb[1], tv2[5]);
    tv2[6] = __hfma2(kh, qb[2], tv2[6]);
    tv2[7] = __hfma2(kh, qb[3], tv2[7]);
}

// read the two packed uint4 of px p (this cg)
__device__ __forceinline__ void ld_raw(const unsigned* q, int p, int cg,
                                       uint4& a, uint4& bu) {
    int ia = p * 32 + ((cg * 8) ^ ((p & 7) << 2));
    a  = *(const uint4*)&q[ia];
    bu = *(const uint4*)&q[ia ^ 4];
}

// unpack two packed uint4 -> 16 f32
__device__ __forceinline__ void unpack_px(uint4 a, uint4 bu, float* qc) {
    const __half2* pa = (const __half2*)&a;
    const __half2* pb = (const __half2*)&bu;
#pragma unroll
    for (int j = 0; j < 4; ++j) {
        float2 f = __half22float2(pa[j]);
        qc[2 * j] = f.x; qc[2 * j + 1] = f.y;
    }
#pragma unroll
    for (int j = 0; j < 4; ++j) {
        float2 f = __half22float2(pb[j]);
        qc[8 + 2 * j] = f.x; qc[8 + 2 * j + 1] = f.y;
    }
}

// pack 16 scaled channels into two uint4 (8 x half2)
__device__ __forceinline__ void pack_px(const float* u, float scale,
                                        uint4& a, uint4& bu) {
    __half2* pa = (__half2*)&a;
    __half2* pb = (__half2*)&bu;
    pa[0] = __floats2half2_rn(u[0]  * scale, u[1]  * scale);
    pa[1] = __floats2half2_rn(u[2]  * scale, u[3]  * scale);
    pa[2] = __floats2half2_rn(u[4]  * scale, u[5]  * scale);
    pa[3] = __floats2half2_rn(u[6]  * scale, u[7]  * scale);
    pb[0] = __floats2half2_rn(u[8]  * scale, u[9]  * scale);
    pb[1] = __floats2half2_rn(u[10] * scale, u[11] * scale);
    pb[2] = __floats2half2_rn(u[12] * scale, u[13] * scale);
    pb[3] = __floats2half2_rn(u[14] * scale, u[15] * scale);
}

__device__ __forceinline__ void st_raw(unsigned* q, int p, int cg,
                                       uint4 a, uint4 bu) {
    int ia = p * 32 + ((cg * 8) ^ ((p & 7) << 2));
    *(uint4*)&q[ia] = a;
    *(uint4*)&q[ia ^ 4] = bu;
}

__device__ __forceinline__ void st_px(unsigned* q, int p, int cg,
                                      const float* u, float scale) {
    uint4 a, bu;
    pack_px(u, scale, a, bu);
    st_raw(q, p, cg, a, bu);
}

// 4-way exclusive prefix + totals over channel-groups (shfl partners at
// pxl+16g share the same task id -> divergence-safe in partial rounds)
__device__ __forceinline__ void scan4(float Aloc, float Bloc, int pxl, int cg,
                                      float& Ar, float& Br, float& T, float& E) {
    float A0 = __shfl(Aloc, pxl),      A1 = __shfl(Aloc, pxl + 16),
          A2 = __shfl(Aloc, pxl + 32), A3 = __shfl(Aloc, pxl + 48);
    float B0 = __shfl(Bloc, pxl),      B1 = __shfl(Bloc, pxl + 16),
          B2 = __shfl(Bloc, pxl + 32), B3 = __shfl(Bloc, pxl + 48);
    T = A0 + A1 + A2 + A3;  E = B0 + B1 + B2 + B3;
    Ar = 0.f; Br = 0.f;
    if (cg > 0) { Ar += A0; Br += B0; }
    if (cg > 1) { Ar += A1; Br += B1; }
    if (cg > 2) { Ar += A2; Br += B2; }
}

// tv[i] = t[e] (pre-scaled by log2e via kaff); qc = q0 center (softmax of the
// ORIGINAL logits). q_new[d] = qc[d]*2^(-qhat2[d])/sum == softmax(lg - q_hat).
// NOTE: the base MUST be q0, not the previous iteration's q (r16 bug).
__device__ __forceinline__ float finish_mult(float* tv, const float* qc,
                                             int pxl, int cg) {
    float Aloc = 0.f, Bloc = 0.f;
#pragma unroll
    for (int i = 0; i < 16; ++i) {
        float e = (float)(cg * 16 + i);
        Aloc += tv[i]; Bloc += e * tv[i];
    }
    float Ar, Br, T, E;
    scan4(Aloc, Bloc, pxl, cg, Ar, Br, T, E);
    float s = 0.f;
#pragma unroll
    for (int i = 0; i < 16; ++i) {
        float e = (float)(cg * 16 + i);
        Ar += tv[i]; Br += e * tv[i];
        float qh2 = 2.f * (e * Ar - Br) + E - e * T;   // = q_hat * log2e
        tv[i] = qc[i] * fexp2(-qh2);
        s += tv[i];
    }
    s += __shfl_xor(s, 16);
    s += __shfl_xor(s, 32);
    return 1.f / s;
}

__device__ __forceinline__ void load_k(const float* kfb, int n, int gy, int gx,
                                       float* k) {
#pragma unroll
    for (int j = 0; j < 9; ++j) k[j] = kfb[(size_t)j * HWN + n];
    if (gy <= 0)      { k[0] = k[1] = k[2] = 0.f; }
    if (gy >= HH - 1) { k[6] = k[7] = k[8] = 0.f; }
    if (gx <= 0)      { k[0] = k[3] = k[6] = 0.f; }
    if (gx >= WW - 1) { k[2] = k[5] = k[8] = 0.f; }
}

// 9-tap stencil from an LDS q-region into tv[16] (f32), via packed f16 FMA
__device__ __forceinline__ void stencil9(const unsigned* qs, int rowstride,
                                         int py, int px, int cg,
                                         const float* k, float* tv) {
    __half2 tv2[8];
#pragma unroll
    for (int j = 0; j < 8; ++j) tv2[j] = __float2half2_rn(0.f);
    int base = (py + 1) * rowstride + (px + 1);
#pragma unroll
    for (int tap = 0; tap < 9; ++tap) {
        int dy = tap / 3 - 1, dx = tap - (tap / 3) * 3 - 1;
        acc_tap(qs, base + dy * rowstride + dx, cg, __float2half2_rn(k[tap]), tv2);
    }
#pragma unroll
    for (int j = 0; j < 8; ++j) {
        float2 f = __half22float2(tv2[j]);
        tv[2 * j] = f.x; tv[2 * j + 1] = f.y;
    }
}

// ---------------------------------------------------------------------------
// Fused CRF per 8x16 out-tile (task = 1 px, 4 lanes x 16 ch), 512 threads.
// Single aliased LDS buffer (30.7 KB): holds q0 during P0/P1, then q1.
//   P0: q0 = softmax(logits) on 12x20 -> LDS
//   P1: q1 = normalize(q0_center * 2^-qhat1), qhat1 from q0 stencil  (correct
//       multiplicative form: base IS softmax(logits))
//       + each thread stashes q0 center of its P2 pixel in regs      [barrier]
//       store q1 into the same LDS buffer                            [barrier]
//   P2: qhat2 from q1 stencil; q2 = normalize(q0c_regs * 2^-qhat2) -> global
// P1/P2 never read logits; exp is raw v_exp_f32 via kaff log2e pre-scale.
// ---------------------------------------------------------------------------
__global__ __launch_bounds__(512) void fused_crf_kernel(
    const float* __restrict__ logits, const float* __restrict__ kaff,
    float* __restrict__ qout)
{
    __shared__ unsigned qs[NP0 * 32];   // 30,720 B (q0, later q1)

    const int t = threadIdx.x;
    const int lane = t & 63;
    const int wv = t >> 6;          // 0..7
    const int pxl = lane & 15;
    const int cg = lane >> 4;       // channels [16cg, 16cg+16)
    const int b = blockIdx.y;
    const int tid16 = wv * 16 + pxl;  // 0..127

    const int bid = blockIdx.x;     // XCD swizzle (1408 % 8 == 0 -> bijective)
    const int pb = (bid & 7) * (NTILES / 8) + (bid >> 3);
    const int tyr = pb / NTX, txc = pb - tyr * NTX;
    const int y0 = tyr * TY, x0 = txc * TX;

    const float* lgb = logits + ((size_t)b * DD + cg * 16) * HWN;
    const float* kfb = kaff + (size_t)b * 9 * HWN;

    // ---------------- P0: q0 = softmax(logits) on 12x20 ----------------
    for (int r = 0; r < 2; ++r) {
        int id = r * 128 + tid16;
        if (id < NP0) {
            int py = id / RX0, px = id - py * RX0;
            int gy = min(max(y0 - 2 + py, 0), HH - 1);
            int gx = min(max(x0 - 2 + px, 0), WW - 1);
            const float* lg = lgb + gy * WW + gx;
            float v[16];
            float s = 0.f;
#pragma unroll
            for (int i = 0; i < 16; ++i) {
                v[i] = __expf(lg[(size_t)i * HWN]);
                s += v[i];
            }
            s += __shfl_xor(s, 16);
            s += __shfl_xor(s, 32);
            st_px(qs, id, cg, v, 1.0f / s);
        }
    }
    __syncthreads();

    // ---------------- P1: q1 on 10x18, results in regs ----------------
    uint4 aA, buA;
    {   // round A: id = tid16 (0..127, always < NP1)
        int py = tid16 / RX1, px = tid16 - py * RX1;
        int gy = y0 - 1 + py, gx = x0 - 1 + px;
        int cy = min(max(gy, 0), HH - 1), cx = min(max(gx, 0), WW - 1);
        int n = cy * WW + cx;
        float k[9];
        load_k(kfb, n, gy, gx, k);
        float tv[16];
        stencil9(qs, RX0, py, px, cg, k, tv);
        uint4 ca, cb2;
        ld_raw(qs, (py + 1) * RX0 + (px + 1), cg, ca, cb2);
        float qc[16];
        unpack_px(ca, cb2, qc);
        float inv = finish_mult(tv, qc, pxl, cg);
        pack_px(tv, inv, aA, buA);
    }
    const int idB = 128 + tid16;
    const bool validB = idB < NP1;
    uint4 aB, buB;
    if (validB) {   // round B partial; shfl partners share id -> safe
        int py = idB / RX1, px = idB - py * RX1;
        int gy = y0 - 1 + py, gx = x0 - 1 + px;
        int cy = min(max(gy, 0), HH - 1), cx = min(max(gx, 0), WW - 1);
        int n = cy * WW + cx;
        float k[9];
        load_k(kfb, n, gy, gx, k);
        float tv[16];
        stencil9(qs, RX0, py, px, cg, k, tv);
        uint4 ca, cb2;
        ld_raw(qs, (py + 1) * RX0 + (px + 1), cg, ca, cb2);
        float qc[16];
        unpack_px(ca, cb2, qc);
        float inv = finish_mult(tv, qc, pxl, cg);
        pack_px(tv, inv, aB, buB);
    }

    // stash q0 center of this thread's P2 pixel (base for P2's softmax)
    uint4 q0cA, q0cB;
    {
        int pyc = tid16 >> 4, pxc = tid16 & 15;          // P2 pixel
        ld_raw(qs, (pyc + 2) * RX0 + (pxc + 2), cg, q0cA, q0cB);
    }
    __syncthreads();   // all q0 reads complete -> buffer reusable

    st_raw(qs, tid16, cg, aA, buA);
    if (validB) st_raw(qs, idB, cg, aB, buB);
    __syncthreads();   // q1 fully written

    // ---------------- P2: q2 -> global, 8x16 ----------------
    {
        int py = tid16 >> 4, px = tid16 & 15;
        int gy = y0 + py, gx = x0 + px;      // always in image
        int n = gy * WW + gx;

        float k[9];
        load_k(kfb, n, gy, gx, k);

        float tv[16];
        stencil9(qs, RX1, py, px, cg, k, tv);
        float qc[16];
        unpack_px(q0cA, q0cB, qc);           // base = q0 (original softmax)
        float inv = finish_mult(tv, qc, pxl, cg);

        float* qo = qout + ((size_t)b * DD + cg * 16) * HWN + n;
#pragma unroll
        for (int i = 0; i < 16; ++i) qo[(size_t)i * HWN] = tv[i] * inv;
    }
}

// ---------------------------------------------------------------------------
extern "C" void kernel_launch(void* const* d_in, const int* in_sizes, int n_in,
                              void* d_out, int out_size, void* d_ws, size_t ws_size,
                              hipStream_t stream) {
    const float* color  = (const float*)d_in[0];
    // d_in[1] = feats: unused by the forward pass
    const float* logits = (const float*)d_in[2];
    const float* wsp    = (const float*)d_in[3];

    float* q_out = (float*)d_out;
    float* kaff  = (float*)d_ws;          // [B,9,HW] f32, 13 MB

    dim3 gridA(HWN / 256, BB);
    affinity_kernel<<<gridA, 256, 0, stream>>>(color, wsp, kaff);

    dim3 gridF(NTILES, BB);               // 1408 tiles x 2 batches
    fused_crf_kernel<<<gridF, 512, 0, stream>>>(logits, kaff, q_out);
}

// Round 18
// 80.208 us; speedup vs baseline: 1.6499x; 1.0021x over previous
//
#include <hip/hip_runtime.h>
#include <hip/hip_fp16.h>

#define HH 256
#define WW 704
#define DD 64
#define CC 3
#define BB 2
#define HWN (HH * WW)       // 180224

#define TY 8                // out-tile rows
#define TX 16               // out-tile cols
#define RY0 12              // q0 region rows (tile + 2*2 halo)
#define RX0 20              // q0 region cols
#define NP0 (RY0 * RX0)     // 240
#define RY1 10              // q1 region rows (tile + 2*1 halo)
#define RX1 18              // q1 region cols
#define NP1 (RY1 * RX1)     // 180
#define NTX (WW / TX)       // 44
#define NTY (HH / TY)       // 32
#define NTILES (NTX * NTY)  // 1408 (divisible by 8 -> bijective XCD swizzle)

static constexpr float INV2Z2 = 1.0f / (2.0f * 1e-3f * 1e-3f);
static constexpr float LOG2E  = 1.4426950408889634f;

__device__ __forceinline__ float fexp2(float x) {
#if __has_builtin(__builtin_amdgcn_exp2f)
    return __builtin_amdgcn_exp2f(x);
#else
    return __expf(x * 0.6931471805599453f);
#endif
}

// ---------------------------------------------------------------------------
// Affinity: kaffp[(b*HWN+n)*12 + tap] = LOG2E * ws * exp(-ssd/(2 zeta^2)).
// PX-MAJOR, stride 12 floats (48 B, 16B-aligned): the fused kernel reads all
// 9 taps of one px as 3 x float4 from one cacheline-pair (was: 9 strided
// plane loads 700KB apart). log2e pre-scale -> iteration exp is raw 2^-x.
// ---------------------------------------------------------------------------
__global__ __launch_bounds__(256) void affinity_kernel(
    const float* __restrict__ color, const float* __restrict__ wsp,
    float* __restrict__ kaffp)
{
    int n = blockIdx.x * 256 + threadIdx.x;
    int b = blockIdx.y;
    int h = n / WW, w = n - h * WW;
    float wsv = wsp[0] * LOG2E;

    const float* cb = color + (size_t)b * CC * HWN + n;
    float c0 = cb[0], c1 = cb[HWN], c2 = cb[2 * HWN];
    bool hm = h > 0, hp = h < HH - 1, wm = w > 0, wp = w < WW - 1;

    float kk[9];
#pragma unroll
    for (int dh = -1; dh <= 1; ++dh) {
#pragma unroll
        for (int dw = -1; dw <= 1; ++dw) {
            int k = (dh + 1) * 3 + (dw + 1);
            bool valid = (dh < 0 ? hm : (dh > 0 ? hp : true)) &&
                         (dw < 0 ? wm : (dw > 0 ? wp : true));
            int off = valid ? (dh * WW + dw) : 0;
            float u0 = valid ? cb[off] : 0.f;
            float u1 = valid ? cb[HWN + off] : 0.f;
            float u2 = valid ? cb[2 * HWN + off] : 0.f;
            float d0 = u0 - c0, d1 = u1 - c1, d2 = u2 - c2;
            float ss = d0 * d0 + d1 * d1 + d2 * d2;
            kk[k] = wsv * __expf(-ss * INV2Z2);
        }
    }
    float* kp = kaffp + ((size_t)b * HWN + n) * 12;
    *(float4*)(kp + 0) = make_float4(kk[0], kk[1], kk[2], kk[3]);
    *(float4*)(kp + 4) = make_float4(kk[4], kk[5], kk[6], kk[7]);
    *(float4*)(kp + 8) = make_float4(kk[8], 0.f, 0.f, 0.f);
}

// ---------------------------------------------------------------------------
// LDS layout: px-major, 32 dwords (64 f16 ch) per px, XOR swizzle on dword
// index: dw(p,q) = p*32 + (q ^ ((p&7)<<2)). Same permutation on store and
// load -> correctness independent of the mixing.
// ---------------------------------------------------------------------------
__device__ __forceinline__ void acc_tap(const unsigned* q, int p0, int cg,
                                        __half2 kh, __half2* tv2) {
    int ia = p0 * 32 + ((cg * 8) ^ ((p0 & 7) << 2));
    int ib = ia ^ 4;
    const __half2* qa = (const __half2*)&q[ia];
    const __half2* qb = (const __half2*)&q[ib];
    tv2[0] = __hfma2(kh, qa[0], tv2[0]);
    tv2[1] = __hfma2(kh, qa[1], tv2[1]);
    tv2[2] = __hfma2(kh, qa[2], tv2[2]);
    tv2[3] = __hfma2(kh, qa[3], tv2[3]);
    tv2[4] = __hfma2(kh, qb[0], tv2[4]);
    tv2[5] = __hfma2(kh, qb[1], tv2[5]);
    tv2[6] = __hfma2(kh, qb[2], tv2[6]);
    tv2[7] = __hfma2(kh, qb[3], tv2[7]);
}

// read the two packed uint4 of px p (this cg)
__device__ __forceinline__ void ld_raw(const unsigned* q, int p, int cg,
                                       uint4& a, uint4& bu) {
    int ia = p * 32 + ((cg * 8) ^ ((p & 7) << 2));
    a  = *(const uint4*)&q[ia];
    bu = *(const uint4*)&q[ia ^ 4];
}

// unpack two packed uint4 -> 16 f32
__device__ __forceinline__ void unpack_px(uint4 a, uint4 bu, float* qc) {
    const __half2* pa = (const __half2*)&a;
    const __half2* pb = (const __half2*)&bu;
#pragma unroll
    for (int j = 0; j < 4; ++j) {
        float2 f = __half22float2(pa[j]);
        qc[2 * j] = f.x; qc[2 * j + 1] = f.y;
    }
#pragma unroll
    for (int j = 0; j < 4; ++j) {
        float2 f = __half22float2(pb[j]);
        qc[8 + 2 * j] = f.x; qc[8 + 2 * j + 1] = f.y;
    }
}

// pack 16 scaled channels into two uint4 (8 x half2)
__device__ __forceinline__ void pack_px(const float* u, float scale,
                                        uint4& a, uint4& bu) {
    __half2* pa = (__half2*)&a;
    __half2* pb = (__half2*)&bu;
    pa[0] = __floats2half2_rn(u[0]  * scale, u[1]  * scale);
    pa[1] = __floats2half2_rn(u[2]  * scale, u[3]  * scale);
    pa[2] = __floats2half2_rn(u[4]  * scale, u[5]  * scale);
    pa[3] = __floats2half2_rn(u[6]  * scale, u[7]  * scale);
    pb[0] = __floats2half2_rn(u[8]  * scale, u[9]  * scale);
    pb[1] = __floats2half2_rn(u[10] * scale, u[11] * scale);
    pb[2] = __floats2half2_rn(u[12] * scale, u[13] * scale);
    pb[3] = __floats2half2_rn(u[14] * scale, u[15] * scale);
}

__device__ __forceinline__ void st_raw(unsigned* q, int p, int cg,
                                       uint4 a, uint4 bu) {
    int ia = p * 32 + ((cg * 8) ^ ((p & 7) << 2));
    *(uint4*)&q[ia] = a;
    *(uint4*)&q[ia ^ 4] = bu;
}

__device__ __forceinline__ void st_px(unsigned* q, int p, int cg,
                                      const float* u, float scale) {
    uint4 a, bu;
    pack_px(u, scale, a, bu);
    st_raw(q, p, cg, a, bu);
}

// 4-way exclusive prefix + totals over channel-groups (shfl partners at
// pxl+16g share the same task id -> divergence-safe in partial rounds)
__device__ __forceinline__ void scan4(float Aloc, float Bloc, int pxl, int cg,
                                      float& Ar, float& Br, float& T, float& E) {
    float A0 = __shfl(Aloc, pxl),      A1 = __shfl(Aloc, pxl + 16),
          A2 = __shfl(Aloc, pxl + 32), A3 = __shfl(Aloc, pxl + 48);
    float B0 = __shfl(Bloc, pxl),      B1 = __shfl(Bloc, pxl + 16),
          B2 = __shfl(Bloc, pxl + 32), B3 = __shfl(Bloc, pxl + 48);
    T = A0 + A1 + A2 + A3;  E = B0 + B1 + B2 + B3;
    Ar = 0.f; Br = 0.f;
    if (cg > 0) { Ar += A0; Br += B0; }
    if (cg > 1) { Ar += A1; Br += B1; }
    if (cg > 2) { Ar += A2; Br += B2; }
}

// tv[i] = t[e] (pre-scaled by log2e via kaff); qc = q0 center (softmax of the
// ORIGINAL logits). q_new[d] = qc[d]*2^(-qhat2[d])/sum == softmax(lg - q_hat).
// NOTE: the base MUST be q0, not the previous iteration's q (r16 bug).
__device__ __forceinline__ float finish_mult(float* tv, const float* qc,
                                             int pxl, int cg) {
    float Aloc = 0.f, Bloc = 0.f;
#pragma unroll
    for (int i = 0; i < 16; ++i) {
        float e = (float)(cg * 16 + i);
        Aloc += tv[i]; Bloc += e * tv[i];
    }
    float Ar, Br, T, E;
    scan4(Aloc, Bloc, pxl, cg, Ar, Br, T, E);
    float s = 0.f;
#pragma unroll
    for (int i = 0; i < 16; ++i) {
        float e = (float)(cg * 16 + i);
        Ar += tv[i]; Br += e * tv[i];
        float qh2 = 2.f * (e * Ar - Br) + E - e * T;   // = q_hat * log2e
        tv[i] = qc[i] * fexp2(-qh2);
        s += tv[i];
    }
    s += __shfl_xor(s, 16);
    s += __shfl_xor(s, 32);
    return 1.f / s;
}

// px-major kaff: 3 x float4 from one 48B record; border masks applied after
__device__ __forceinline__ void load_k(const float* kfbp, int n, int gy, int gx,
                                       float* k) {
    const float* kp = kfbp + (size_t)n * 12;
    float4 a = *(const float4*)(kp + 0);
    float4 bq = *(const float4*)(kp + 4);
    float4 c = *(const float4*)(kp + 8);
    k[0] = a.x; k[1] = a.y; k[2] = a.z; k[3] = a.w;
    k[4] = bq.x; k[5] = bq.y; k[6] = bq.z; k[7] = bq.w;
    k[8] = c.x;
    if (gy <= 0)      { k[0] = k[1] = k[2] = 0.f; }
    if (gy >= HH - 1) { k[6] = k[7] = k[8] = 0.f; }
    if (gx <= 0)      { k[0] = k[3] = k[6] = 0.f; }
    if (gx >= WW - 1) { k[2] = k[5] = k[8] = 0.f; }
}

// 9-tap stencil from an LDS q-region into tv[16] (f32), via packed f16 FMA
__device__ __forceinline__ void stencil9(const unsigned* qs, int rowstride,
                                         int py, int px, int cg,
                                         const float* k, float* tv) {
    __half2 tv2[8];
#pragma unroll
    for (int j = 0; j < 8; ++j) tv2[j] = __float2half2_rn(0.f);
    int base = (py + 1) * rowstride + (px + 1);
#pragma unroll
    for (int tap = 0; tap < 9; ++tap) {
        int dy = tap / 3 - 1, dx = tap - (tap / 3) * 3 - 1;
        acc_tap(qs, base + dy * rowstride + dx, cg, __float2half2_rn(k[tap]), tv2);
    }
#pragma unroll
    for (int j = 0; j < 8; ++j) {
        float2 f = __half22float2(tv2[j]);
        tv[2 * j] = f.x; tv[2 * j + 1] = f.y;
    }
}

// ---------------------------------------------------------------------------
// Fused CRF per 8x16 out-tile (task = 1 px, 4 lanes x 16 ch), 512 threads.
// Single aliased LDS buffer (30.7 KB): holds q0 during P0/P1, then q1.
//   P0: q0 = softmax(logits) on 12x20 -> LDS
//   P1: q1 = normalize(q0_center * 2^-qhat1), qhat1 from q0 stencil
//       + each thread stashes q0 center of its P2 pixel in regs      [barrier]
//       store q1 into the same LDS buffer                            [barrier]
//   P2: qhat2 from q1 stencil; q2 = normalize(q0c_regs * 2^-qhat2) -> global
// P1/P2 never read logits; exp is raw v_exp_f32 via kaff log2e pre-scale.
// ---------------------------------------------------------------------------
__global__ __launch_bounds__(512) void fused_crf_kernel(
    const float* __restrict__ logits, const float* __restrict__ kaffp,
    float* __restrict__ qout)
{
    __shared__ unsigned qs[NP0 * 32];   // 30,720 B (q0, later q1)

    const int t = threadIdx.x;
    const int lane = t & 63;
    const int wv = t >> 6;          // 0..7
    const int pxl = lane & 15;
    const int cg = lane >> 4;       // channels [16cg, 16cg+16)
    const int b = blockIdx.y;
    const int tid16 = wv * 16 + pxl;  // 0..127

    const int bid = blockIdx.x;     // XCD swizzle (1408 % 8 == 0 -> bijective)
    const int pb = (bid & 7) * (NTILES / 8) + (bid >> 3);
    const int tyr = pb / NTX, txc = pb - tyr * NTX;
    const int y0 = tyr * TY, x0 = txc * TX;

    const float* lgb = logits + ((size_t)b * DD + cg * 16) * HWN;
    const float* kfbp = kaffp + (size_t)b * HWN * 12;

    // ---------------- P0: q0 = softmax(logits) on 12x20 ----------------
    for (int r = 0; r < 2; ++r) {
        int id = r * 128 + tid16;
        if (id < NP0) {
            int py = id / RX0, px = id - py * RX0;
            int gy = min(max(y0 - 2 + py, 0), HH - 1);
            int gx = min(max(x0 - 2 + px, 0), WW - 1);
            const float* lg = lgb + gy * WW + gx;
            float v[16];
            float s = 0.f;
#pragma unroll
            for (int i = 0; i < 16; ++i) {
                v[i] = __expf(lg[(size_t)i * HWN]);
                s += v[i];
            }
            s += __shfl_xor(s, 16);
            s += __shfl_xor(s, 32);
            st_px(qs, id, cg, v, 1.0f / s);
        }
    }
    __syncthreads();

    // ---------------- P1: q1 on 10x18, results in regs ----------------
    uint4 aA, buA;
    {   // round A: id = tid16 (0..127, always < NP1)
        int py = tid16 / RX1, px = tid16 - py * RX1;
        int gy = y0 - 1 + py, gx = x0 - 1 + px;
        int cy = min(max(gy, 0), HH - 1), cx = min(max(gx, 0), WW - 1);
        int n = cy * WW + cx;
        float k[9];
        load_k(kfbp, n, gy, gx, k);
        float tv[16];
        stencil9(qs, RX0, py, px, cg, k, tv);
        uint4 ca, cb2;
        ld_raw(qs, (py + 1) * RX0 + (px + 1), cg, ca, cb2);
        float qc[16];
        unpack_px(ca, cb2, qc);
        float inv = finish_mult(tv, qc, pxl, cg);
        pack_px(tv, inv, aA, buA);
    }
    const int idB = 128 + tid16;
    const bool validB = idB < NP1;
    uint4 aB, buB;
    if (validB) {   // round B partial; shfl partners share id -> safe
        int py = idB / RX1, px = idB - py * RX1;
        int gy = y0 - 1 + py, gx = x0 - 1 + px;
        int cy = min(max(gy, 0), HH - 1), cx = min(max(gx, 0), WW - 1);
        int n = cy * WW + cx;
        float k[9];
        load_k(kfbp, n, gy, gx, k);
        float tv[16];
        stencil9(qs, RX0, py, px, cg, k, tv);
        uint4 ca, cb2;
        ld_raw(qs, (py + 1) * RX0 + (px + 1), cg, ca, cb2);
        float qc[16];
        unpack_px(ca, cb2, qc);
        float inv = finish_mult(tv, qc, pxl, cg);
        pack_px(tv, inv, aB, buB);
    }

    // stash q0 center of this thread's P2 pixel (base for P2's softmax)
    uint4 q0cA, q0cB;
    {
        int pyc = tid16 >> 4, pxc = tid16 & 15;          // P2 pixel
        ld_raw(qs, (pyc + 2) * RX0 + (pxc + 2), cg, q0cA, q0cB);
    }
    __syncthreads();   // all q0 reads complete -> buffer reusable

    st_raw(qs, tid16, cg, aA, buA);
    if (validB) st_raw(qs, idB, cg, aB, buB);
    __syncthreads();   // q1 fully written

    // ---------------- P2: q2 -> global, 8x16 ----------------
    {
        int py = tid16 >> 4, px = tid16 & 15;
        int gy = y0 + py, gx = x0 + px;      // always in image
        int n = gy * WW + gx;

        float k[9];
        load_k(kfbp, n, gy, gx, k);

        float tv[16];
        stencil9(qs, RX1, py, px, cg, k, tv);
        float qc[16];
        unpack_px(q0cA, q0cB, qc);           // base = q0 (original softmax)
        float inv = finish_mult(tv, qc, pxl, cg);

        float* qo = qout + ((size_t)b * DD + cg * 16) * HWN + n;
#pragma unroll
        for (int i = 0; i < 16; ++i) qo[(size_t)i * HWN] = tv[i] * inv;
    }
}

// ---------------------------------------------------------------------------
extern "C" void kernel_launch(void* const* d_in, const int* in_sizes, int n_in,
                              void* d_out, int out_size, void* d_ws, size_t ws_size,
                              hipStream_t stream) {
    const float* color  = (const float*)d_in[0];
    // d_in[1] = feats: unused by the forward pass
    const float* logits = (const float*)d_in[2];
    const float* wsp    = (const float*)d_in[3];

    float* q_out = (float*)d_out;
    float* kaffp = (float*)d_ws;          // [B,HW,12] f32 px-major, 17.3 MB

    dim3 gridA(HWN / 256, BB);
    affinity_kernel<<<gridA, 256, 0, stream>>>(color, wsp, kaffp);

    dim3 gridF(NTILES, BB);               // 1408 tiles x 2 batches
    fused_crf_kernel<<<gridF, 512, 0, stream>>>(logits, kaffp, q_out);
}